// Round 14
// baseline (17494.688 us; speedup 1.0000x reference)
//
#include <hip/hip_runtime.h>
#include <hip/hip_bf16.h>

typedef unsigned int uint32;
typedef unsigned short u16;
typedef unsigned long long u64;
typedef __attribute__((ext_vector_type(8))) short s16x8;
typedef __attribute__((ext_vector_type(4))) float f32x4;

#define H    768
#define H2   1536
#define H3   2304
#define H6   4608
#define BB   8
#define SS   128
#define GG   1024
#define NWG  256
#define NT   256
#define NTM  512
#define INVSCALE 0.036084391824351615f
#define SPIN_LIMIT (1 << 17)
#define DYN_LDS 163200

struct IN {
  const int *chat_ids, *speaker_info, *inputs;
  const float *emb, *d_wih, *d_whh, *d_bih, *d_bhh;
  const float *g_wih, *g_whh, *g_bih, *g_bhh;
  const float *s_wih, *s_whh, *s_bih, *s_bhh;
  const float *wq, *bq, *wk, *bk, *wv, *bv;
  const float *h0, *d_h0, *attn_h;
};

struct WS {
  int *flags1;
  float *Mqk, *Gsum;
  float *cu, *vkq, *cb, *cvs, *ch0s, *cvg, *chg0, *ghs0;
  float *Ms, *Mg;
  float *gi_d, *GIS;           // aliased region
  uint32 *gi_bf, *U_bf;        // bf16x2-packed copies
  float *dialogue, *U, *cvec, *GIG;
  float *gh_dbuf;              // [2][BB][H3]
  float *sp_global;            // [8][H2]
  float *op_buf;               // [SS][H]
  u64 *op_tag;                 // [NWG]   ep16 + 3xbf16 op broadcast
  u64 *h_tag;                  // [2*NWG] ep16 + 3xbf16 h broadcast
  u64 *sc_tag;                 // [2][SS] epoch-tagged scores (parity dbuf)
  float *probs_buf;
  float *h_buf, *Wbuf, *AO;
  float *out_op, *out_spop;
};

__device__ inline float sigm(float x) { return 1.f / (1.f + expf(-x)); }

__device__ inline u16 f2bf(float v) {
  __hip_bfloat16 b = __float2bfloat16(v);
  return *reinterpret_cast<u16*>(&b);
}
__device__ inline uint32 pack2bf(float a, float b) {
  return (uint32)f2bf(a) | ((uint32)f2bf(b) << 16);
}
__device__ inline float bf2f(uint32 u) { return __uint_as_float(u << 16); }

// ---- agent-scope write-through accessors ----
__device__ inline float2 ld2(const float* p) { return *(const float2*)p; }
__device__ inline float2 ald2(const float* p) {
  u64 v = __hip_atomic_load((const u64*)p, __ATOMIC_RELAXED, __HIP_MEMORY_SCOPE_AGENT);
  union { u64 u; float2 f; } c; c.u = v; return c.f;
}
__device__ inline float ald(const float* p) {
  return __hip_atomic_load(p, __ATOMIC_RELAXED, __HIP_MEMORY_SCOPE_AGENT);
}
__device__ inline void ast(float* p, float v) {
  __hip_atomic_store(p, v, __ATOMIC_RELAXED, __HIP_MEMORY_SCOPE_AGENT);
}
__device__ inline void ast64(u64* p, u64 v) {
  __hip_atomic_store(p, v, __ATOMIC_RELAXED, __HIP_MEMORY_SCOPE_AGENT);
}
__device__ inline u64 ald64(const u64* p) {
  return __hip_atomic_load(p, __ATOMIC_RELAXED, __HIP_MEMORY_SCOPE_AGENT);
}
__device__ inline u64 tagf(int ep, float v) {
  return ((u64)(uint32)ep << 32) | (u64)__float_as_uint(v);
}
// ep16 + 3xbf16 payload
__device__ inline u64 tag3(int ep, float a, float b, float c) {
  return ((u64)(uint32)ep << 48) | ((u64)f2bf(c) << 32) | ((u64)f2bf(b) << 16) | (u64)f2bf(a);
}

// 32-bit-epoch poll (sc tags)
__device__ inline float pollf(const u64* p, int ep, int& bail) {
  int spins = 0;
  u64 v;
  for (;;) {
    v = ald64(p);
    if ((int)(v >> 32) >= ep) break;
    if (++spins > SPIN_LIMIT) { bail = 1; break; }
  }
  return __uint_as_float((uint32)v);
}
// 16-bit-epoch poll (op/h tags)
__device__ inline u64 poll48(const u64* p, int ep, int& bail) {
  int spins = 0;
  u64 v;
  for (;;) {
    v = ald64(p);
    if ((int)(v >> 48) >= ep) break;
    if (++spins > SPIN_LIMIT) { bail = 1; break; }
  }
  return v;
}

// ---- flat grid barrier for rnnD ----
__device__ inline void gbar2(int* flags, int epoch, int& dead) {
  int bail = 0;
  __syncthreads();
  if (!dead) {
    if (threadIdx.x == 0)
      __hip_atomic_store(&flags[blockIdx.x * 16], epoch, __ATOMIC_RELAXED, __HIP_MEMORY_SCOPE_AGENT);
    if (threadIdx.x < NWG) {
      int spins = 0;
      while (__hip_atomic_load(&flags[threadIdx.x * 16], __ATOMIC_RELAXED, __HIP_MEMORY_SCOPE_AGENT) < epoch) {
        if (++spins > SPIN_LIMIT) { bail = 1; break; }
      }
    }
  }
  dead |= __syncthreads_or(bail);
  asm volatile("" ::: "memory");
}

// ---- register-x dot helpers ----
template <int NI>
__device__ inline float dotr(const u16* wcol, const float2* xr) {
  const uint32* wp = (const uint32*)wcol;
  int l = threadIdx.x & 63;
  float acc = 0.f;
  #pragma unroll
  for (int i = 0; i < NI; i++) {
    uint32 u = wp[i * 64 + l];
    acc = fmaf(xr[i].x, __uint_as_float(u << 16),
          fmaf(xr[i].y, __uint_as_float(u & 0xffff0000u), acc));
  }
  #pragma unroll
  for (int o = 32; o > 0; o >>= 1) acc += __shfl_down(acc, o);
  return acc;  // valid on lane 0
}
__device__ inline float xreduce(float a) {
  #pragma unroll
  for (int o = 32; o > 0; o >>= 1) a += __shfl_xor(a, o);
  return a;  // valid on all lanes
}
template <int NI>
__device__ inline void loadx_lds(float2* xr, const float* x) {
  int l = threadIdx.x & 63;
  #pragma unroll
  for (int i = 0; i < NI; i++) xr[i] = ld2(x + 2 * (i * 64 + l));
}
template <int NI>
__device__ inline void loadx_atm(float2* xr, const float* x) {
  int l = threadIdx.x & 63;
  #pragma unroll
  for (int i = 0; i < NI; i++) xr[i] = ald2(x + 2 * (i * 64 + l));
}

// ================= prep kernels =================

__global__ __launch_bounds__(NT) void prep1_k(IN in, WS w) {
  long i = (long)blockIdx.x * NT + threadIdx.x;
  const long NG = (long)H3 * H;
  if (i < NG) {
    long n = i / H, k = i - n * H;
    w.Gsum[i] = in.g_wih[n * H3 + H + k] + in.g_wih[n * H3 + 2 * H + k];
  } else if (i < NG + H) {
    int m = (int)(i - NG);
    float a = 0.f;
    for (int t = 0; t < H; t++) a = fmaf(in.bq[t], in.wk[(long)t * H + m], a);
    w.cu[m] = a;
  } else if (i < NG + 2 * H) {
    int m = (int)(i - NG - H);
    float a = 0.f;
    for (int t = 0; t < H; t++) a = fmaf(in.bk[t], in.wq[(long)t * H + m], a);
    w.vkq[m] = a;
  } else if (i == NG + 2 * H) {
    float a = 0.f;
    for (int t = 0; t < H; t++) a = fmaf(in.bk[t], in.bq[t], a);
    w.cb[0] = a;
  }
}

__global__ __launch_bounds__(NT) void prep2_k(IN in, WS w) {
  int wid = blockIdx.x * (NT / 64) + (threadIdx.x >> 6);
  int l = threadIdx.x & 63;
  const int R1 = H6, R2 = H6 + H3, R3 = H6 + H3 + H6;
  if (wid < R1) {
    const float* row = in.s_wih + (long)wid * H2;
    float a = 0.f, c = 0.f;
    for (int i = l; i < H; i += 64) { float rv = row[i]; a = fmaf(in.bv[i], rv, a); c = fmaf(in.attn_h[i], rv, c); }
    #pragma unroll
    for (int o = 32; o > 0; o >>= 1) { a += __shfl_down(a, o); c += __shfl_down(c, o); }
    if (l == 0) { w.cvs[wid] = a; w.ch0s[wid] = c; }
  } else if (wid < R2) {
    int k = wid - R1;
    const float* row = in.g_wih + (long)k * H3;
    float a = 0.f, c = 0.f;
    for (int i = l; i < H; i += 64) { float rv = row[i]; a = fmaf(in.bv[i], rv, a); c = fmaf(in.attn_h[i], rv, c); }
    #pragma unroll
    for (int o = 32; o > 0; o >>= 1) { a += __shfl_down(a, o); c += __shfl_down(c, o); }
    if (l == 0) { w.cvg[k] = a; w.chg0[k] = c; }
  } else if (wid < R3) {
    int k = wid - R2;
    const float* row = in.s_whh + (long)k * H2;
    float a = 0.f;
    for (int i = l; i < H2; i += 64) a = fmaf(in.h0[i], row[i], a);
    #pragma unroll
    for (int o = 32; o > 0; o >>= 1) a += __shfl_down(a, o);
    if (l == 0) w.ghs0[k] = a + in.s_bhh[k];
  }
}

__global__ __launch_bounds__(NT) void pack_k(const float* src, uint32* dst, long n2) {
  long i = (long)blockIdx.x * NT + threadIdx.x;
  if (i < n2) dst[i] = pack2bf(src[2 * i], src[2 * i + 1]);
}

// ---- f32 GEMM (kept only for Mqk: col-major A) ----
__global__ __launch_bounds__(NT) void gemm_k(const float* A, long sAm, long sAk,
                                             const float* B, long sBk,
                                             float* C, int M, int N, int K) {
  __shared__ float As[16][65];
  __shared__ float Bs[16][65];
  int m0 = blockIdx.y * 64, n0 = blockIdx.x * 64;
  int tid = threadIdx.x;
  int tx = tid & 15, ty = tid >> 4;
  float acc[4][4] = {};
  for (int k0 = 0; k0 < K; k0 += 16) {
    {
      int m = tid & 63, kb = tid >> 6;
      for (int p = 0; p < 4; p++) {
        int k = kb + p * 4;
        As[k][m] = A[(long)(m0 + m) * sAm + (long)(k0 + k) * sAk];
      }
    }
    {
      int n = tid & 63, kb = tid >> 6;
      for (int p = 0; p < 4; p++) {
        int k = kb + p * 4;
        Bs[k][n] = B[(long)(k0 + k) * sBk + (n0 + n)];
      }
    }
    __syncthreads();
    #pragma unroll
    for (int k = 0; k < 16; k++) {
      float a[4], b[4];
      #pragma unroll
      for (int i = 0; i < 4; i++) a[i] = As[k][ty * 4 + i];
      #pragma unroll
      for (int j = 0; j < 4; j++) b[j] = Bs[k][tx * 4 + j];
      #pragma unroll
      for (int i = 0; i < 4; i++)
        #pragma unroll
        for (int j = 0; j < 4; j++) acc[i][j] = fmaf(a[i], b[j], acc[i][j]);
    }
    __syncthreads();
  }
  for (int i = 0; i < 4; i++)
    for (int j = 0; j < 4; j++) {
      int m = m0 + ty * 4 + i, n = n0 + tx * 4 + j;
      C[(long)m * N + n] = acc[i][j];
    }
}

// ---- MFMA bf16 GEMM ----
__global__ __launch_bounds__(NT) void mgemm_k(const float* A, long sAm, const int* gather,
                                              const float* B, long sB, int bColMajor,
                                              const float* bias, float* C, int N, int K) {
  __shared__ u16 Al[128 * 40];
  __shared__ u16 Bl[128 * 40];
  int tid = threadIdx.x;
  int n0 = blockIdx.x * 128, m0 = blockIdx.y * 128;
  int l = tid & 63, wv = tid >> 6;
  int wr = wv >> 1, wc = wv & 1;
  f32x4 acc[4][4] = {};
  long arow = gather ? (long)gather[m0 + (tid >> 1)] : (long)(m0 + (tid >> 1));
  for (int k0 = 0; k0 < K; k0 += 32) {
    __syncthreads();
    {
      int r = tid >> 1, half = tid & 1;
      const float* src = A + arow * sAm + k0 + half * 16;
      uint32* dst = (uint32*)(Al + r * 40 + half * 16);
      #pragma unroll
      for (int j = 0; j < 8; j++) dst[j] = pack2bf(src[2 * j], src[2 * j + 1]);
    }
    if (bColMajor) {
      int n = tid >> 1, half = tid & 1;
      const float* src = B + (long)(n0 + n) * sB + k0 + half * 16;
      uint32* dst = (uint32*)(Bl + n * 40 + half * 16);
      #pragma unroll
      for (int j = 0; j < 8; j++) dst[j] = pack2bf(src[2 * j], src[2 * j + 1]);
    } else {
      int kk = tid & 31, nb = tid >> 5;
      const float* src = B + (long)(k0 + kk) * sB + n0 + nb * 16;
      #pragma unroll
      for (int j = 0; j < 16; j++) Bl[(nb * 16 + j) * 40 + kk] = f2bf(src[j]);
    }
    __syncthreads();
    s16x8 af[4], bf[4];
    #pragma unroll
    for (int i = 0; i < 4; i++) {
      af[i] = *(const s16x8*)(Al + (wr * 64 + i * 16 + (l & 15)) * 40 + (l >> 4) * 8);
      bf[i] = *(const s16x8*)(Bl + (wc * 64 + i * 16 + (l & 15)) * 40 + (l >> 4) * 8);
    }
    #pragma unroll
    for (int i = 0; i < 4; i++)
      #pragma unroll
      for (int j = 0; j < 4; j++)
        acc[i][j] = __builtin_amdgcn_mfma_f32_16x16x32_bf16(af[i], bf[j], acc[i][j], 0, 0, 0);
  }
  #pragma unroll
  for (int i = 0; i < 4; i++)
    #pragma unroll
    for (int j = 0; j < 4; j++) {
      int n = n0 + wc * 64 + j * 16 + (l & 15);
      int mb = m0 + wr * 64 + i * 16 + ((l >> 4) << 2);
      float bb = bias ? bias[n] : 0.f;
      #pragma unroll
      for (int r = 0; r < 4; r++)
        C[(long)(mb + r) * N + n] = acc[i][j][r] + bb;
    }
}

// ================= sequential kernels =================

__global__ __launch_bounds__(NTM) void coop_rnnD(IN in, WS w) {
  __shared__ u16 wD[9 * H];
  __shared__ float hB[BB][H];
  int tid = threadIdx.x, wg = blockIdx.x;
  int c0 = wg * 9;
  int l = tid & 63, wv = tid >> 6;
  for (int i = tid; i < 9 * H; i += NTM)
    wD[i] = f2bf(in.d_whh[(long)(c0 + i / H) * H + (i % H)]);
  __syncthreads();
  int epoch = 1, dead = 0;
  for (int t = 0; t < SS; t++) {
    if (t > 0) {
      float* ghb = w.gh_dbuf + (size_t)(t & 1) * BB * H3;
      for (int tk = wv; tk < 72; tk += 8) {
        int b = tk / 9, j = tk - b * 9;
        float2 xr[6];
        loadx_lds<6>(xr, hB[b]);
        float val = dotr<6>(wD + j * H, xr);
        if (l == 0) ast(ghb + (long)b * H3 + c0 + j, val + in.d_bhh[c0 + j]);
      }
      gbar2(w.flags1, epoch++, dead);
    }
    const float* ghb = w.gh_dbuf + (size_t)(t & 1) * BB * H3;
    for (int pc = tid; pc < BB * H / 2; pc += NTM) {
      int b = pc / (H / 2), k = 2 * (pc - b * (H / 2));
      const uint32* gi = w.gi_bf + ((long)(b * SS + t)) * (H3 / 2);
      uint32 u0 = gi[k >> 1], u1 = gi[(H + k) >> 1], u2 = gi[(2 * H + k) >> 1];
      float gr0 = __uint_as_float(u0 << 16), gr1 = __uint_as_float(u0 & 0xffff0000u);
      float gz0 = __uint_as_float(u1 << 16), gz1 = __uint_as_float(u1 & 0xffff0000u);
      float gn0 = __uint_as_float(u2 << 16), gn1 = __uint_as_float(u2 & 0xffff0000u);
      float hr0, hr1, hz0, hz1, hn0, hn1;
      if (t == 0) {
        hr0 = in.d_bhh[k]; hr1 = in.d_bhh[k + 1];
        hz0 = in.d_bhh[H + k]; hz1 = in.d_bhh[H + k + 1];
        hn0 = in.d_bhh[2 * H + k]; hn1 = in.d_bhh[2 * H + k + 1];
      } else {
        const float* gb = ghb + (long)b * H3;
        float2 a0 = ald2(gb + k), a1 = ald2(gb + H + k), a2 = ald2(gb + 2 * H + k);
        hr0 = a0.x; hr1 = a0.y; hz0 = a1.x; hz1 = a1.y; hn0 = a2.x; hn1 = a2.y;
      }
      float p0 = (t == 0) ? 0.f : hB[b][k], p1 = (t == 0) ? 0.f : hB[b][k + 1];
      float r0 = sigm(gr0 + hr0), r1 = sigm(gr1 + hr1);
      float z0 = sigm(gz0 + hz0), z1 = sigm(gz1 + hz1);
      float n0 = tanhf(gn0 + r0 * hn0), n1 = tanhf(gn1 + r1 * hn1);
      float h0v = (1.f - z0) * n0 + z0 * p0, h1v = (1.f - z1) * n1 + z1 * p1;
      hB[b][k] = h0v; hB[b][k + 1] = h1v;
      if (wg == 0) *(float2*)(w.dialogue + ((long)(b * SS + t)) * H + k) = make_float2(h0v, h1v);
    }
    __syncthreads();
  }
}

// Distributed-gate main loop; ep16+3xbf16 tags, 1 poll per thread, 3 barriers/step.
// WG owns g-cols [wg*3,+3), s-cols [wg*6,+6).
__global__ __launch_bounds__(NTM) void coop_main(IN in, WS w) {
  extern __shared__ char Lds[];
  u16*   wShh  = (u16*)(Lds + 0);        // [18][1536]
  u16*   wGab  = (u16*)(Lds + 55296);    // [9][1536]
  u16*   wMs   = (u16*)(Lds + 82944);    // [18][768]
  u16*   wMg   = (u16*)(Lds + 110592);   // [9][768]
  u16*   wGhh  = (u16*)(Lds + 124416);   // [9][768]
  float* OPMSl = (float*)(Lds + 138240); // [128][19]
  float* OPMGl = (float*)(Lds + 147968); // [128][9]
  float* h_lds = (float*)(Lds + 152576); // [1536]
  float* op_lds= (float*)(Lds + 158720); // [768]
  float* el    = (float*)(Lds + 161792); // [128]
  float* red   = (float*)(Lds + 162304); // [64] (unused)
  float* loc_si  = (float*)(Lds + 162560); // [18]
  float* loc_ghs = (float*)(Lds + 162632); // [2][18]
  float* loc_gw  = (float*)(Lds + 162776); // [9]
  float* loc_ghg = (float*)(Lds + 162812); // [9]
  float* loc_gih = (float*)(Lds + 162848); // [9] (unused now)
  float* loc_gis = (float*)(Lds + 162884); // [18]
  float* loc_gig = (float*)(Lds + 162956); // [9]
  float* spc     = (float*)(Lds + 162992); // [8][6]

  int tid = threadIdx.x, wg = blockIdx.x;
  int l = tid & 63, wv = tid >> 6;
  int c0s = wg * 6, c0g3 = wg * 3;
  auto rrS = [&](int j) { return (j / 6) * H2 + c0s + (j % 6); };
  auto rrG = [&](int j) { return (j / 3) * H + c0g3 + (j % 3); };

  for (int i = tid; i < 18 * H2; i += NTM) { int j = i / H2, k = i - j * H2; wShh[i] = f2bf(in.s_whh[(long)rrS(j) * H2 + k]); }
  for (int i = tid; i < 9 * H2;  i += NTM) { int j = i / H2, k = i - j * H2; wGab[i] = f2bf(in.g_wih[(long)rrG(j) * H3 + k]); }
  for (int i = tid; i < 18 * H;  i += NTM) { int j = i / H,  k = i - j * H;  wMs[i]  = f2bf(w.Ms[(long)rrS(j) * H + k]); }
  for (int i = tid; i < 9 * H;   i += NTM) { int j = i / H,  k = i - j * H;  wMg[i]  = f2bf(w.Mg[(long)rrG(j) * H + k]); }
  for (int i = tid; i < 9 * H;   i += NTM) { int j = i / H,  k = i - j * H;  wGhh[i] = f2bf(in.g_whh[(long)rrG(j) * H + k]); }
  for (int i = tid; i < H; i += NTM) op_lds[i] = in.d_h0[i];
  __syncthreads();

  int dead = 0;
  float opw[3];  // lane 0 of wave 0 keeps the exact f32 op recurrence state
  if (wv == 0 && l == 0) {
    opw[0] = in.d_h0[c0g3]; opw[1] = in.d_h0[c0g3 + 1]; opw[2] = in.d_h0[c0g3 + 2];
  }

  for (int g = 0; g < GG; g++) {
    int s = g & 127, b = g >> 7;
    int g1 = g + 1, s1 = g1 & 127;
    int spk_cur = in.speaker_info[in.chat_ids[b] * SS + s];
    int spk_next = (g1 < GG) ? in.speaker_info[in.chat_ids[g1 >> 7] * SS + s1] : 0;
    float cv = w.cvec[g];
    if (tid < 18) loc_gis[tid] = w.GIS[(long)g * H6 + rrS(tid)];

    // ---- PH1: 1 tag per thread ----
    int bail = 0;
    if (!dead) {
      if (g > 0 && tid < 256) {
        u64 v = poll48(w.op_tag + tid, g, bail);
        op_lds[3 * tid]     = bf2f((uint32)(v & 0xffffu));
        op_lds[3 * tid + 1] = bf2f((uint32)((v >> 16) & 0xffffu));
        op_lds[3 * tid + 2] = bf2f((uint32)((v >> 32) & 0xffffu));
      } else if (tid >= 384 && s >= 1) {
        int j = tid - 384;
        if (j <= s - 2)
          el[j] = expf(fminf(pollf(w.sc_tag + (size_t)(g & 1) * SS + j, g, bail), 30.f));
      }
    }
    dead |= __syncthreads_or(bail);  // A

    if (s >= 1) {
      // ---- fused stage: every wave self-contained ----
      float2 xr[6];
      loadx_lds<6>(xr, op_lds);
      float a = 0.f;
      {
        const uint32* Ub = w.U_bf + (long)g * (H / 2);
        #pragma unroll
        for (int i = 0; i < 6; i++) {
          uint32 u = Ub[i * 64 + l];
          int idx = 2 * (i * 64 + l);
          a = fmaf(op_lds[idx], __uint_as_float(u << 16),
              fmaf(op_lds[idx + 1], __uint_as_float(u & 0xffff0000u), a));
        }
        a = xreduce(a);
      }
      float e1 = expf(fminf(a + cv, 30.f));
      float bs = 0.f;
      if (l <= s - 2) bs = el[l];
      if (l + 64 <= s - 2) bs += el[l + 64];
      bs = xreduce(bs);
      float suinv = 1.f / (e1 + bs + expf(fminf(cv, 30.f)));

      for (int r = wv; r < 36; r += 8) {
        if (r < 18) {
          float nr = dotr<6>(wMs + r * H, xr);
          float aa = 0.f;
          if (l <= s - 2) aa = el[l] * OPMSl[l * 19 + r];
          if (l + 64 <= s - 2) aa = fmaf(el[l + 64], OPMSl[(l + 64) * 19 + r], aa);
          #pragma unroll
          for (int o = 32; o > 0; o >>= 1) aa += __shfl_down(aa, o);
          if (l == 0) {
            OPMSl[(s - 1) * 19 + r] = nr;
            loc_si[r] = (aa + e1 * nr) * suinv + w.cvs[rrS(r)];
          }
        } else if (r < 27) {
          int t = r - 18;
          float nr = dotr<6>(wMg + t * H, xr);
          float aa = 0.f;
          if (l <= s - 2) aa = el[l] * OPMGl[l * 9 + t];
          if (l + 64 <= s - 2) aa = fmaf(el[l + 64], OPMGl[(l + 64) * 9 + t], aa);
          #pragma unroll
          for (int o = 32; o > 0; o >>= 1) aa += __shfl_down(aa, o);
          if (l == 0) {
            OPMGl[(s - 1) * 9 + t] = nr;
            loc_gw[t] = (aa + e1 * nr) * suinv + w.cvg[rrG(t)];
          }
        } else {
          int t = r - 27;
          float v = dotr<6>(wGhh + t * H, xr);
          if (l == 0) loc_ghg[t] = v + in.g_bhh[rrG(t)];
        }
      }
      if (g1 < GG && s1 != 0 && spk_next != spk_cur) {
        float2 xs[12];
        loadx_atm<12>(xs, w.sp_global + (long)spk_next * H2);
        for (int t = wv; t < 18; t += 8) {
          float v = dotr<12>(wShh + t * H2, xs);
          if (l == 0) loc_ghs[(g1 & 1) * 18 + t] = v + in.s_bhh[rrS(t)];
        }
      }
      if (wv == 7 && g1 < GG && s1 >= 2 && wg < s) {
        const float* opr = w.op_buf + (long)wg * H;
        const uint32* Ub1 = w.U_bf + (long)g1 * (H / 2);
        float a2 = 0.f;
        #pragma unroll
        for (int i0 = 0; i0 < 6; i0++) {
          int idx = i0 * 64 + l;
          float2 xa = ald2(opr + 2 * idx);
          uint32 u = Ub1[idx];
          a2 = fmaf(xa.x, __uint_as_float(u << 16),
               fmaf(xa.y, __uint_as_float(u & 0xffff0000u), a2));
        }
        #pragma unroll
        for (int o = 32; o > 0; o >>= 1) a2 += __shfl_down(a2, o);
        if (l == 0) ast64(w.sc_tag + (size_t)(g1 & 1) * SS + wg, tagf(g1, a2 + w.cvec[g1]));
      }
      if (wg == 0 && wv == 6) {
        int j = l;
        float pv = (j <= s - 2) ? el[j] * suinv : ((j == s - 1) ? e1 * suinv : 0.f);
        w.probs_buf[(long)g * SS + j] = pv;
        j = l + 64;
        pv = (j <= s - 2) ? el[j] * suinv : ((j == s - 1) ? e1 * suinv : 0.f);
        w.probs_buf[(long)g * SS + j] = pv;
      }
      __syncthreads();  // D
    } else {
      // s == 0: batch start
      if (tid < 18) loc_si[tid] = w.ch0s[rrS(tid)];
      else if (tid >= 32 && tid < 41) loc_gw[tid - 32] = w.chg0[rrG(tid - 32)];
      if (tid >= 64 && tid < 112) { int x = (tid - 64) / 6, t2 = (tid - 64) % 6; spc[x * 6 + t2] = in.h0[c0s + t2]; }
      if (tid >= 128 && tid < 176) {
        int x = (tid - 128) / 6, t2 = (tid - 128) % 6;
        if (x != spk_cur) ast(w.sp_global + (long)x * H2 + c0s + t2, in.h0[c0s + t2]);
      }
      if (wv == 3) {
        float2 xr[6];
        loadx_lds<6>(xr, op_lds);
        for (int j = 0; j < 9; j++) {
          float val = dotr<6>(wGhh + j * H, xr);
          if (l == 0) loc_ghg[j] = val + in.g_bhh[rrG(j)];
        }
      }
      if (wg == 0 && tid >= 384) w.probs_buf[(long)g * SS + (tid - 384)] = 0.f;
      __syncthreads();  // D
    }

    // ---- s-gate: own 6 output cols; pack to 2 h-tags via shfl ----
    float hn_val = 0.f;
    if (tid < 6) {
      int c = c0s + tid;
      float hprev = spc[spk_cur * 6 + tid];
      float ghr, ghz, ghn;
      if (s == 0) { ghr = w.ghs0[c]; ghz = w.ghs0[H2 + c]; ghn = w.ghs0[2 * H2 + c]; }
      else { const float* gb = loc_ghs + (g & 1) * 18; ghr = gb[tid]; ghz = gb[6 + tid]; ghn = gb[12 + tid]; }
      float gir = loc_gis[tid] + loc_si[tid];
      float giz = loc_gis[6 + tid] + loc_si[6 + tid];
      float gin = loc_gis[12 + tid] + loc_si[12 + tid];
      float r = sigm(gir + ghr), z = sigm(giz + ghz);
      float n = tanhf(gin + r * ghn);
      float hn = (1.f - z) * n + z * hprev;
      spc[spk_cur * 6 + tid] = hn;
      ast(w.sp_global + (long)spk_cur * H2 + c, hn);
      w.h_buf[(long)g * H2 + c] = hn;
      hn_val = hn;
    }
    if (wv == 0) {
      float p0 = __shfl(hn_val, 0), p1 = __shfl(hn_val, 1), p2 = __shfl(hn_val, 2);
      float p3 = __shfl(hn_val, 3), p4 = __shfl(hn_val, 4), p5 = __shfl(hn_val, 5);
      if (l == 0) ast64(w.h_tag + 2 * wg, tag3(g1, p0, p1, p2));
      else if (l == 1) ast64(w.h_tag + 2 * wg + 1, tag3(g1, p3, p4, p5));
    }

    // ---- PH2: 1 h-tag per thread ----
    if (tid < 9) loc_gig[tid] = w.GIG[(long)g * H3 + rrG(tid)];
    bail = 0;
    if (!dead) {
      u64 v = poll48(w.h_tag + tid, g1, bail);
      h_lds[3 * tid]     = bf2f((uint32)(v & 0xffffu));
      h_lds[3 * tid + 1] = bf2f((uint32)((v >> 16) & 0xffffu));
      h_lds[3 * tid + 2] = bf2f((uint32)((v >> 32) & 0xffffu));
    }
    dead |= __syncthreads_or(bail);  // E

    if (wv == 0) {
      // op path self-contained in wave 0: 9 Gab dots + gate + tag store
      float2 xh[12];
      loadx_lds<12>(xh, h_lds);
      float gih[9];
      #pragma unroll
      for (int j = 0; j < 9; j++) gih[j] = dotr<12>(wGab + j * H2, xh);
      if (l == 0) {
        #pragma unroll
        for (int t = 0; t < 3; t++) {
          float gir = loc_gig[t]     + loc_gw[t]     + gih[t];
          float giz = loc_gig[3 + t] + loc_gw[3 + t] + gih[3 + t];
          float gin = loc_gig[6 + t] + loc_gw[6 + t] + gih[6 + t];
          float r = sigm(gir + loc_ghg[t]);
          float z = sigm(giz + loc_ghg[3 + t]);
          float n = tanhf(gin + r * loc_ghg[6 + t]);
          float o = (1.f - z) * n + z * opw[t];
          opw[t] = o;
          ast(w.op_buf + (long)s * H + c0g3 + t, o);
          w.out_op[(long)g * H + c0g3 + t] = o;
        }
      }
      asm volatile("s_waitcnt vmcnt(0)" ::: "memory");
      if (l == 0) ast64(w.op_tag + wg, tag3(g1, opw[0], opw[1], opw[2]));
    } else {
      // waves 1-7: s_whh dots for next step (consumed after next barriers)
      int needsh = (g1 < GG && s1 != 0 && (spk_next == spk_cur || s == 0)) ? 1 : 0;
      if (needsh) {
        float2 xs[12];
        if (spk_next != spk_cur) loadx_atm<12>(xs, w.sp_global + (long)spk_next * H2);
        else loadx_lds<12>(xs, h_lds);
        for (int r = wv - 1; r < 18; r += 7) {
          float val = dotr<12>(wShh + r * H2, xs);
          if (l == 0) loc_ghs[(g1 & 1) * 18 + r] = val + in.s_bhh[rrS(r)];
        }
      }
    }
    // no barrier F: next iteration's barrier A orders everything
  }
}

// ================= epilogue =================

__global__ __launch_bounds__(NT) void fixup_u_k(WS w) {
  long i = (long)blockIdx.x * NT + threadIdx.x;
  if (i < (long)GG * H) {
    int m = (int)(i % H);
    w.U[i] = (w.U[i] + w.cu[m]) * INVSCALE;
  }
}

__global__ __launch_bounds__(NT) void cvec_k(WS w) {
  int g = blockIdx.x * 4 + (threadIdx.x >> 6);
  int l = threadIdx.x & 63;
  const float* d = w.dialogue + (long)g * H;
  float p = 0.f;
  for (int i = l; i < H; i += 64) p = fmaf(d[i], w.vkq[i], p);
  #pragma unroll
  for (int o = 32; o > 0; o >>= 1) p += __shfl_down(p, o);
  if (l == 0) w.cvec[g] = (p + w.cb[0]) * INVSCALE;
}

__global__ __launch_bounds__(NT) void epi_W_k(WS w) {
  int g = blockIdx.x, b = g >> 7;
  __shared__ float pl[SS];
  if (threadIdx.x < SS) pl[threadIdx.x] = w.probs_buf[(long)g * SS + threadIdx.x];
  __syncthreads();
  const float* opb = w.out_op + (long)b * SS * H;
  for (int n = threadIdx.x; n < H; n += NT) {
    float acc = 0.f;
    for (int j = 0; j < SS; j++) acc = fmaf(pl[j], opb[(long)j * H + n], acc);
    w.Wbuf[(long)g * H + n] = acc;
  }
}

__global__ __launch_bounds__(NT) void assemble_k(IN in, WS w) {
  long idx = (long)blockIdx.x * NT + threadIdx.x;
  if (idx >= (long)GG * H2) return;
  long g = idx / H2;
  int k = (int)(idx - g * H2);
  int s = (int)(g & 127);
  float t;
  if (k < H) t = (s == 0) ? in.attn_h[k] : w.AO[g * H + k];
  else t = w.dialogue[g * H + (k - H)];
  w.out_spop[idx] = w.h_buf[idx] + t;
}

// ================= host =================

extern "C" void kernel_launch(void* const* d_in, const int* in_sizes, int n_in,
                              void* d_out, int out_size, void* d_ws, size_t ws_size,
                              hipStream_t stream) {
  IN in;
  in.chat_ids = (const int*)d_in[0];
  in.speaker_info = (const int*)d_in[1];
  in.inputs = (const int*)d_in[4];
  in.emb = (const float*)d_in[5];
  in.d_wih = (const float*)d_in[6];  in.d_whh = (const float*)d_in[7];
  in.d_bih = (const float*)d_in[8];  in.d_bhh = (const float*)d_in[9];
  in.g_wih = (const float*)d_in[10]; in.g_whh = (const float*)d_in[11];
  in.g_bih = (const float*)d_in[12]; in.g_bhh = (const float*)d_in[13];
  in.s_wih = (const float*)d_in[14]; in.s_whh = (const float*)d_in[15];
  in.s_bih = (const float*)d_in[16]; in.s_bhh = (const float*)d_in[17];
  in.wq = (const float*)d_in[18];  in.bq = (const float*)d_in[19];
  in.wk = (const float*)d_in[20];  in.bk = (const float*)d_in[21];
  in.wv = (const float*)d_in[22];  in.bv = (const float*)d_in[23];
  in.h0 = (const float*)d_in[24];  in.d_h0 = (const float*)d_in[25];
  in.attn_h = (const float*)d_in[26];

  char* base = (char*)d_ws;
  size_t off = 0;
  auto A = [&](size_t bytes) -> void* {
    size_t r = (off + 255) & ~(size_t)255;
    off = r + bytes;
    return (void*)(base + r);
  };
  WS w;
  w.flags1 = (int*)A(NWG * 16 * 4);
  w.Mqk = (float*)A((size_t)H * H * 4);
  w.Gsum = (float*)A((size_t)H3 * H * 4);
  w.cu = (float*)A(H * 4);
  w.vkq = (float*)A(H * 4);
  w.cb = (float*)A(4);
  w.cvs = (float*)A(H6 * 4);
  w.ch0s = (float*)A(H6 * 4);
  w.cvg = (float*)A(H3 * 4);
  w.chg0 = (float*)A(H3 * 4);
  w.ghs0 = (float*)A(H6 * 4);
  w.Ms = (float*)A((size_t)H6 * H * 4);
  w.Mg = (float*)A((size_t)H3 * H * 4);
  {
    void* r1 = A((size_t)GG * H6 * 4);  // max(gi_d [GG*H3], GIS [GG*H6])
    w.gi_d = (float*)r1;
    w.GIS = (float*)r1;
  }
  w.gi_bf = (uint32*)A((size_t)GG * H3 * 2);
  w.U_bf = (uint32*)A((size_t)GG * H * 2);
  w.dialogue = (float*)A((size_t)GG * H * 4);
  w.U = (float*)A((size_t)GG * H * 4);
  w.cvec = (float*)A(GG * 4);
  w.GIG = (float*)A((size_t)GG * H3 * 4);
  w.gh_dbuf = (float*)A((size_t)2 * BB * H3 * 4);
  w.sp_global = (float*)A((size_t)BB * H2 * 4);
  w.op_buf = (float*)A((size_t)SS * H * 4);
  w.op_tag = (u64*)A((size_t)NWG * 8);
  w.h_tag = (u64*)A((size_t)2 * NWG * 8);
  w.sc_tag = (u64*)A((size_t)2 * SS * 8);
  w.probs_buf = (float*)A((size_t)GG * SS * 4);
  w.h_buf = (float*)A((size_t)GG * H2 * 4);
  w.Wbuf = (float*)A((size_t)GG * H * 4);
  w.AO = (float*)A((size_t)GG * H * 4);
  w.out_op = (float*)d_out;
  w.out_spop = (float*)d_out + (size_t)GG * H;

  (void)hipFuncSetAttribute((const void*)coop_main, hipFuncAttributeMaxDynamicSharedMemorySize, DYN_LDS);

  (void)hipMemsetAsync(w.flags1, 0, NWG * 16 * 4, stream);
  (void)hipMemsetAsync(w.op_tag, 0, (size_t)NWG * 8, stream);
  (void)hipMemsetAsync(w.h_tag, 0, (size_t)2 * NWG * 8, stream);
  (void)hipMemsetAsync(w.sc_tag, 0, (size_t)2 * SS * 8, stream);

  const long NG = (long)H3 * H;
  prep1_k<<<(int)((NG + 2 * H + 1 + NT - 1) / NT), NT, 0, stream>>>(in, w);
  prep2_k<<<(H6 + H3 + H6 + 3) / 4, NT, 0, stream>>>(in, w);

  // Mqk = wq^T @ wk
  gemm_k<<<dim3(H / 64, H / 64), NT, 0, stream>>>(in.wq, 1, H, in.wk, H, w.Mqk, H, H, H);
  // Ms = s_wihA @ wv ; Mg = g_wihA @ wv
  mgemm_k<<<dim3(H / 128, H6 / 128), NT, 0, stream>>>(in.s_wih, H2, nullptr, in.wv, H, 0, nullptr, w.Ms, H, H);
  mgemm_k<<<dim3(H / 128, H3 / 128), NT, 0, stream>>>(in.g_wih, H3, nullptr, in.wv, H, 0, nullptr, w.Mg, H, H);
  // gi_d = emb[inputs] @ d_wih^T + d_bih, then pack to bf16x2
  mgemm_k<<<dim3(H3 / 128, GG / 128), NT, 0, stream>>>(in.emb, H, in.inputs, in.d_wih, H, 1, in.d_bih, w.gi_d, H3, H);
  pack_k<<<(int)(((long)GG * H3 / 2 + NT - 1) / NT), NT, 0, stream>>>(w.gi_d, w.gi_bf, (long)GG * H3 / 2);
  coop_rnnD<<<NWG, NTM, 0, stream>>>(in, w);

  // U = dialogue @ Mqk ; GIS = dialogue @ s_wihB^T + s_bih ; GIG = dialogue @ Gsum^T + g_bih
  mgemm_k<<<dim3(H / 128, GG / 128), NT, 0, stream>>>(w.dialogue, H, nullptr, w.Mqk, H, 0, nullptr, w.U, H, H);
  mgemm_k<<<dim3(H6 / 128, GG / 128), NT, 0, stream>>>(w.dialogue, H, nullptr, in.s_wih + H, H2, 1, in.s_bih, w.GIS, H6, H);
  mgemm_k<<<dim3(H3 / 128, GG / 128), NT, 0, stream>>>(w.dialogue, H, nullptr, w.Gsum, H, 1, in.g_bih, w.GIG, H3, H);
  fixup_u_k<<<(GG * H + NT - 1) / NT, NT, 0, stream>>>(w);
  pack_k<<<(int)(((long)GG * H / 2 + NT - 1) / NT), NT, 0, stream>>>(w.U, w.U_bf, (long)GG * H / 2);
  cvec_k<<<GG / 4, NT, 0, stream>>>(w);

  coop_main<<<NWG, NTM, DYN_LDS, stream>>>(in, w);

  epi_W_k<<<GG, NT, 0, stream>>>(w);
  // AO = Wbuf @ wv^T + bv
  mgemm_k<<<dim3(H / 128, GG / 128), NT, 0, stream>>>(w.Wbuf, H, nullptr, in.wv, H, 1, in.bv, w.AO, H, H);
  assemble_k<<<(int)(((long)GG * H2 + NT - 1) / NT), NT, 0, stream>>>(in, w);
}

// Round 15
// 15886.557 us; speedup vs baseline: 1.1012x; 1.1012x over previous
//
#include <hip/hip_runtime.h>
#include <hip/hip_bf16.h>

typedef unsigned int uint32;
typedef unsigned short u16;
typedef unsigned long long u64;
typedef __attribute__((ext_vector_type(8))) short s16x8;
typedef __attribute__((ext_vector_type(4))) float f32x4;

#define H    768
#define H2   1536
#define H3   2304
#define H6   4608
#define BB   8
#define SS   128
#define GG   1024
#define NWG  256
#define NT   256
#define NTM  512
#define INVSCALE 0.036084391824351615f
#define SPIN_LIMIT (1 << 17)
#define DYN_LDS 163200

struct IN {
  const int *chat_ids, *speaker_info, *inputs;
  const float *emb, *d_wih, *d_whh, *d_bih, *d_bhh;
  const float *g_wih, *g_whh, *g_bih, *g_bhh;
  const float *s_wih, *s_whh, *s_bih, *s_bhh;
  const float *wq, *bq, *wk, *bk, *wv, *bv;
  const float *h0, *d_h0, *attn_h;
};

struct WS {
  int *flags1;
  float *Mqk, *Gsum;
  float *cu, *vkq, *cb, *cvs, *ch0s, *cvg, *chg0, *ghs0;
  float *Ms, *Mg;
  float *gi_d, *GIS;           // aliased region
  uint32 *gi_bf, *U_bf;        // bf16x2-packed copies
  float *dialogue, *U, *cvec, *GIG;
  float *gh_dbuf;              // [2][BB][H3]
  float *sp_global;            // [8][H2]
  float *op_buf;               // [SS][H]
  u64 *op_tag;                 // [NWG]   ep16 + 3xbf16 op broadcast
  u64 *h_tag;                  // [2*NWG] ep16 + 3xbf16 h broadcast
  u64 *sc_tag;                 // [2][SS] epoch-tagged scores (parity dbuf)
  float *probs_buf;
  float *h_buf, *Wbuf, *AO;
  float *out_op, *out_spop;
};

__device__ inline float sigm(float x) { return 1.f / (1.f + expf(-x)); }

__device__ inline u16 f2bf(float v) {
  __hip_bfloat16 b = __float2bfloat16(v);
  return *reinterpret_cast<u16*>(&b);
}
__device__ inline uint32 pack2bf(float a, float b) {
  return (uint32)f2bf(a) | ((uint32)f2bf(b) << 16);
}
__device__ inline float bf2f(uint32 u) { return __uint_as_float(u << 16); }

// ---- agent-scope write-through accessors ----
__device__ inline float2 ld2(const float* p) { return *(const float2*)p; }
__device__ inline float2 ald2(const float* p) {
  u64 v = __hip_atomic_load((const u64*)p, __ATOMIC_RELAXED, __HIP_MEMORY_SCOPE_AGENT);
  union { u64 u; float2 f; } c; c.u = v; return c.f;
}
__device__ inline float ald(const float* p) {
  return __hip_atomic_load(p, __ATOMIC_RELAXED, __HIP_MEMORY_SCOPE_AGENT);
}
__device__ inline void ast(float* p, float v) {
  __hip_atomic_store(p, v, __ATOMIC_RELAXED, __HIP_MEMORY_SCOPE_AGENT);
}
__device__ inline void ast64(u64* p, u64 v) {
  __hip_atomic_store(p, v, __ATOMIC_RELAXED, __HIP_MEMORY_SCOPE_AGENT);
}
__device__ inline u64 ald64(const u64* p) {
  return __hip_atomic_load(p, __ATOMIC_RELAXED, __HIP_MEMORY_SCOPE_AGENT);
}
__device__ inline u64 tagf(int ep, float v) {
  return ((u64)(uint32)ep << 32) | (u64)__float_as_uint(v);
}
// ep16 + 3xbf16 payload
__device__ inline u64 tag3(int ep, float a, float b, float c) {
  return ((u64)(uint32)ep << 48) | ((u64)f2bf(c) << 32) | ((u64)f2bf(b) << 16) | (u64)f2bf(a);
}

// 32-bit-epoch poll (sc tags)
__device__ inline float pollf(const u64* p, int ep, int& bail) {
  int spins = 0;
  u64 v;
  for (;;) {
    v = ald64(p);
    if ((int)(v >> 32) >= ep) break;
    if (++spins > SPIN_LIMIT) { bail = 1; break; }
  }
  return __uint_as_float((uint32)v);
}
// 16-bit-epoch poll (op/h tags)
__device__ inline u64 poll48(const u64* p, int ep, int& bail) {
  int spins = 0;
  u64 v;
  for (;;) {
    v = ald64(p);
    if ((int)(v >> 48) >= ep) break;
    if (++spins > SPIN_LIMIT) { bail = 1; break; }
  }
  return v;
}

// ---- flat grid barrier for rnnD ----
__device__ inline void gbar2(int* flags, int epoch, int& dead) {
  int bail = 0;
  __syncthreads();
  if (!dead) {
    if (threadIdx.x == 0)
      __hip_atomic_store(&flags[blockIdx.x * 16], epoch, __ATOMIC_RELAXED, __HIP_MEMORY_SCOPE_AGENT);
    if (threadIdx.x < NWG) {
      int spins = 0;
      while (__hip_atomic_load(&flags[threadIdx.x * 16], __ATOMIC_RELAXED, __HIP_MEMORY_SCOPE_AGENT) < epoch) {
        if (++spins > SPIN_LIMIT) { bail = 1; break; }
      }
    }
  }
  dead |= __syncthreads_or(bail);
  asm volatile("" ::: "memory");
}

// ---- register-x dot helpers ----
template <int NI>
__device__ inline float dotr(const u16* wcol, const float2* xr) {
  const uint32* wp = (const uint32*)wcol;
  int l = threadIdx.x & 63;
  float acc = 0.f;
  #pragma unroll
  for (int i = 0; i < NI; i++) {
    uint32 u = wp[i * 64 + l];
    acc = fmaf(xr[i].x, __uint_as_float(u << 16),
          fmaf(xr[i].y, __uint_as_float(u & 0xffff0000u), acc));
  }
  #pragma unroll
  for (int o = 32; o > 0; o >>= 1) acc += __shfl_down(acc, o);
  return acc;  // valid on lane 0
}
__device__ inline float xreduce(float a) {
  #pragma unroll
  for (int o = 32; o > 0; o >>= 1) a += __shfl_xor(a, o);
  return a;  // valid on all lanes
}
template <int NI>
__device__ inline void loadx_lds(float2* xr, const float* x) {
  int l = threadIdx.x & 63;
  #pragma unroll
  for (int i = 0; i < NI; i++) xr[i] = ld2(x + 2 * (i * 64 + l));
}
template <int NI>
__device__ inline void loadx_atm(float2* xr, const float* x) {
  int l = threadIdx.x & 63;
  #pragma unroll
  for (int i = 0; i < NI; i++) xr[i] = ald2(x + 2 * (i * 64 + l));
}

// ================= prep kernels =================

__global__ __launch_bounds__(NT) void prep1_k(IN in, WS w) {
  long i = (long)blockIdx.x * NT + threadIdx.x;
  const long NG = (long)H3 * H;
  if (i < NG) {
    long n = i / H, k = i - n * H;
    w.Gsum[i] = in.g_wih[n * H3 + H + k] + in.g_wih[n * H3 + 2 * H + k];
  } else if (i < NG + H) {
    int m = (int)(i - NG);
    float a = 0.f;
    for (int t = 0; t < H; t++) a = fmaf(in.bq[t], in.wk[(long)t * H + m], a);
    w.cu[m] = a;
  } else if (i < NG + 2 * H) {
    int m = (int)(i - NG - H);
    float a = 0.f;
    for (int t = 0; t < H; t++) a = fmaf(in.bk[t], in.wq[(long)t * H + m], a);
    w.vkq[m] = a;
  } else if (i == NG + 2 * H) {
    float a = 0.f;
    for (int t = 0; t < H; t++) a = fmaf(in.bk[t], in.bq[t], a);
    w.cb[0] = a;
  }
}

__global__ __launch_bounds__(NT) void prep2_k(IN in, WS w) {
  int wid = blockIdx.x * (NT / 64) + (threadIdx.x >> 6);
  int l = threadIdx.x & 63;
  const int R1 = H6, R2 = H6 + H3, R3 = H6 + H3 + H6;
  if (wid < R1) {
    const float* row = in.s_wih + (long)wid * H2;
    float a = 0.f, c = 0.f;
    for (int i = l; i < H; i += 64) { float rv = row[i]; a = fmaf(in.bv[i], rv, a); c = fmaf(in.attn_h[i], rv, c); }
    #pragma unroll
    for (int o = 32; o > 0; o >>= 1) { a += __shfl_down(a, o); c += __shfl_down(c, o); }
    if (l == 0) { w.cvs[wid] = a; w.ch0s[wid] = c; }
  } else if (wid < R2) {
    int k = wid - R1;
    const float* row = in.g_wih + (long)k * H3;
    float a = 0.f, c = 0.f;
    for (int i = l; i < H; i += 64) { float rv = row[i]; a = fmaf(in.bv[i], rv, a); c = fmaf(in.attn_h[i], rv, c); }
    #pragma unroll
    for (int o = 32; o > 0; o >>= 1) { a += __shfl_down(a, o); c += __shfl_down(c, o); }
    if (l == 0) { w.cvg[k] = a; w.chg0[k] = c; }
  } else if (wid < R3) {
    int k = wid - R2;
    const float* row = in.s_whh + (long)k * H2;
    float a = 0.f;
    for (int i = l; i < H2; i += 64) a = fmaf(in.h0[i], row[i], a);
    #pragma unroll
    for (int o = 32; o > 0; o >>= 1) a += __shfl_down(a, o);
    if (l == 0) w.ghs0[k] = a + in.s_bhh[k];
  }
}

__global__ __launch_bounds__(NT) void pack_k(const float* src, uint32* dst, long n2) {
  long i = (long)blockIdx.x * NT + threadIdx.x;
  if (i < n2) dst[i] = pack2bf(src[2 * i], src[2 * i + 1]);
}

// ---- f32 GEMM (kept only for Mqk: col-major A) ----
__global__ __launch_bounds__(NT) void gemm_k(const float* A, long sAm, long sAk,
                                             const float* B, long sBk,
                                             float* C, int M, int N, int K) {
  __shared__ float As[16][65];
  __shared__ float Bs[16][65];
  int m0 = blockIdx.y * 64, n0 = blockIdx.x * 64;
  int tid = threadIdx.x;
  int tx = tid & 15, ty = tid >> 4;
  float acc[4][4] = {};
  for (int k0 = 0; k0 < K; k0 += 16) {
    {
      int m = tid & 63, kb = tid >> 6;
      for (int p = 0; p < 4; p++) {
        int k = kb + p * 4;
        As[k][m] = A[(long)(m0 + m) * sAm + (long)(k0 + k) * sAk];
      }
    }
    {
      int n = tid & 63, kb = tid >> 6;
      for (int p = 0; p < 4; p++) {
        int k = kb + p * 4;
        Bs[k][n] = B[(long)(k0 + k) * sBk + (n0 + n)];
      }
    }
    __syncthreads();
    #pragma unroll
    for (int k = 0; k < 16; k++) {
      float a[4], b[4];
      #pragma unroll
      for (int i = 0; i < 4; i++) a[i] = As[k][ty * 4 + i];
      #pragma unroll
      for (int j = 0; j < 4; j++) b[j] = Bs[k][tx * 4 + j];
      #pragma unroll
      for (int i = 0; i < 4; i++)
        #pragma unroll
        for (int j = 0; j < 4; j++) acc[i][j] = fmaf(a[i], b[j], acc[i][j]);
    }
    __syncthreads();
  }
  for (int i = 0; i < 4; i++)
    for (int j = 0; j < 4; j++) {
      int m = m0 + ty * 4 + i, n = n0 + tx * 4 + j;
      C[(long)m * N + n] = acc[i][j];
    }
}

// ---- MFMA bf16 GEMM ----
__global__ __launch_bounds__(NT) void mgemm_k(const float* A, long sAm, const int* gather,
                                              const float* B, long sB, int bColMajor,
                                              const float* bias, float* C, int N, int K) {
  __shared__ u16 Al[128 * 40];
  __shared__ u16 Bl[128 * 40];
  int tid = threadIdx.x;
  int n0 = blockIdx.x * 128, m0 = blockIdx.y * 128;
  int l = tid & 63, wv = tid >> 6;
  int wr = wv >> 1, wc = wv & 1;
  f32x4 acc[4][4] = {};
  long arow = gather ? (long)gather[m0 + (tid >> 1)] : (long)(m0 + (tid >> 1));
  for (int k0 = 0; k0 < K; k0 += 32) {
    __syncthreads();
    {
      int r = tid >> 1, half = tid & 1;
      const float* src = A + arow * sAm + k0 + half * 16;
      uint32* dst = (uint32*)(Al + r * 40 + half * 16);
      #pragma unroll
      for (int j = 0; j < 8; j++) dst[j] = pack2bf(src[2 * j], src[2 * j + 1]);
    }
    if (bColMajor) {
      int n = tid >> 1, half = tid & 1;
      const float* src = B + (long)(n0 + n) * sB + k0 + half * 16;
      uint32* dst = (uint32*)(Bl + n * 40 + half * 16);
      #pragma unroll
      for (int j = 0; j < 8; j++) dst[j] = pack2bf(src[2 * j], src[2 * j + 1]);
    } else {
      int kk = tid & 31, nb = tid >> 5;
      const float* src = B + (long)(k0 + kk) * sB + n0 + nb * 16;
      #pragma unroll
      for (int j = 0; j < 16; j++) Bl[(nb * 16 + j) * 40 + kk] = f2bf(src[j]);
    }
    __syncthreads();
    s16x8 af[4], bf[4];
    #pragma unroll
    for (int i = 0; i < 4; i++) {
      af[i] = *(const s16x8*)(Al + (wr * 64 + i * 16 + (l & 15)) * 40 + (l >> 4) * 8);
      bf[i] = *(const s16x8*)(Bl + (wc * 64 + i * 16 + (l & 15)) * 40 + (l >> 4) * 8);
    }
    #pragma unroll
    for (int i = 0; i < 4; i++)
      #pragma unroll
      for (int j = 0; j < 4; j++)
        acc[i][j] = __builtin_amdgcn_mfma_f32_16x16x32_bf16(af[i], bf[j], acc[i][j], 0, 0, 0);
  }
  #pragma unroll
  for (int i = 0; i < 4; i++)
    #pragma unroll
    for (int j = 0; j < 4; j++) {
      int n = n0 + wc * 64 + j * 16 + (l & 15);
      int mb = m0 + wr * 64 + i * 16 + ((l >> 4) << 2);
      float bb = bias ? bias[n] : 0.f;
      #pragma unroll
      for (int r = 0; r < 4; r++)
        C[(long)(mb + r) * N + n] = acc[i][j][r] + bb;
    }
}

// ================= sequential kernels =================

__global__ __launch_bounds__(NTM) void coop_rnnD(IN in, WS w) {
  __shared__ u16 wD[9 * H];
  __shared__ float hB[BB][H];
  int tid = threadIdx.x, wg = blockIdx.x;
  int c0 = wg * 9;
  int l = tid & 63, wv = tid >> 6;
  for (int i = tid; i < 9 * H; i += NTM)
    wD[i] = f2bf(in.d_whh[(long)(c0 + i / H) * H + (i % H)]);
  __syncthreads();
  int epoch = 1, dead = 0;
  for (int t = 0; t < SS; t++) {
    if (t > 0) {
      float* ghb = w.gh_dbuf + (size_t)(t & 1) * BB * H3;
      for (int tk = wv; tk < 72; tk += 8) {
        int b = tk / 9, j = tk - b * 9;
        float2 xr[6];
        loadx_lds<6>(xr, hB[b]);
        float val = dotr<6>(wD + j * H, xr);
        if (l == 0) ast(ghb + (long)b * H3 + c0 + j, val + in.d_bhh[c0 + j]);
      }
      gbar2(w.flags1, epoch++, dead);
    }
    const float* ghb = w.gh_dbuf + (size_t)(t & 1) * BB * H3;
    for (int pc = tid; pc < BB * H / 2; pc += NTM) {
      int b = pc / (H / 2), k = 2 * (pc - b * (H / 2));
      const uint32* gi = w.gi_bf + ((long)(b * SS + t)) * (H3 / 2);
      uint32 u0 = gi[k >> 1], u1 = gi[(H + k) >> 1], u2 = gi[(2 * H + k) >> 1];
      float gr0 = __uint_as_float(u0 << 16), gr1 = __uint_as_float(u0 & 0xffff0000u);
      float gz0 = __uint_as_float(u1 << 16), gz1 = __uint_as_float(u1 & 0xffff0000u);
      float gn0 = __uint_as_float(u2 << 16), gn1 = __uint_as_float(u2 & 0xffff0000u);
      float hr0, hr1, hz0, hz1, hn0, hn1;
      if (t == 0) {
        hr0 = in.d_bhh[k]; hr1 = in.d_bhh[k + 1];
        hz0 = in.d_bhh[H + k]; hz1 = in.d_bhh[H + k + 1];
        hn0 = in.d_bhh[2 * H + k]; hn1 = in.d_bhh[2 * H + k + 1];
      } else {
        const float* gb = ghb + (long)b * H3;
        float2 a0 = ald2(gb + k), a1 = ald2(gb + H + k), a2 = ald2(gb + 2 * H + k);
        hr0 = a0.x; hr1 = a0.y; hz0 = a1.x; hz1 = a1.y; hn0 = a2.x; hn1 = a2.y;
      }
      float p0 = (t == 0) ? 0.f : hB[b][k], p1 = (t == 0) ? 0.f : hB[b][k + 1];
      float r0 = sigm(gr0 + hr0), r1 = sigm(gr1 + hr1);
      float z0 = sigm(gz0 + hz0), z1 = sigm(gz1 + hz1);
      float n0 = tanhf(gn0 + r0 * hn0), n1 = tanhf(gn1 + r1 * hn1);
      float h0v = (1.f - z0) * n0 + z0 * p0, h1v = (1.f - z1) * n1 + z1 * p1;
      hB[b][k] = h0v; hB[b][k + 1] = h1v;
      if (wg == 0) *(float2*)(w.dialogue + ((long)(b * SS + t)) * H + k) = make_float2(h0v, h1v);
    }
    __syncthreads();
  }
}

// Distributed-gate main loop; ep16+3xbf16 tags (1 poll/thread) + R13 stage shape.
// WG owns g-cols [wg*3,+3), s-cols [wg*6,+6).
__global__ __launch_bounds__(NTM) void coop_main(IN in, WS w) {
  extern __shared__ char Lds[];
  u16*   wShh  = (u16*)(Lds + 0);        // [18][1536]
  u16*   wGab  = (u16*)(Lds + 55296);    // [9][1536]
  u16*   wMs   = (u16*)(Lds + 82944);    // [18][768]
  u16*   wMg   = (u16*)(Lds + 110592);   // [9][768]
  u16*   wGhh  = (u16*)(Lds + 124416);   // [9][768]
  float* OPMSl = (float*)(Lds + 138240); // [128][19]
  float* OPMGl = (float*)(Lds + 147968); // [128][9]
  float* h_lds = (float*)(Lds + 152576); // [1536]
  float* op_lds= (float*)(Lds + 158720); // [768]
  float* el    = (float*)(Lds + 161792); // [128]
  float* red   = (float*)(Lds + 162304); // [64] (unused)
  float* loc_si  = (float*)(Lds + 162560); // [18]
  float* loc_ghs = (float*)(Lds + 162632); // [2][18]
  float* loc_gw  = (float*)(Lds + 162776); // [9]
  float* loc_ghg = (float*)(Lds + 162812); // [9]
  float* loc_gih = (float*)(Lds + 162848); // [9]
  float* loc_gis = (float*)(Lds + 162884); // [18]
  float* loc_gig = (float*)(Lds + 162956); // [9]
  float* spc     = (float*)(Lds + 162992); // [8][6]

  int tid = threadIdx.x, wg = blockIdx.x;
  int l = tid & 63, wv = tid >> 6;
  int c0s = wg * 6, c0g3 = wg * 3;
  auto rrS = [&](int j) { return (j / 6) * H2 + c0s + (j % 6); };
  auto rrG = [&](int j) { return (j / 3) * H + c0g3 + (j % 3); };

  for (int i = tid; i < 18 * H2; i += NTM) { int j = i / H2, k = i - j * H2; wShh[i] = f2bf(in.s_whh[(long)rrS(j) * H2 + k]); }
  for (int i = tid; i < 9 * H2;  i += NTM) { int j = i / H2, k = i - j * H2; wGab[i] = f2bf(in.g_wih[(long)rrG(j) * H3 + k]); }
  for (int i = tid; i < 18 * H;  i += NTM) { int j = i / H,  k = i - j * H;  wMs[i]  = f2bf(w.Ms[(long)rrS(j) * H + k]); }
  for (int i = tid; i < 9 * H;   i += NTM) { int j = i / H,  k = i - j * H;  wMg[i]  = f2bf(w.Mg[(long)rrG(j) * H + k]); }
  for (int i = tid; i < 9 * H;   i += NTM) { int j = i / H,  k = i - j * H;  wGhh[i] = f2bf(in.g_whh[(long)rrG(j) * H + k]); }
  for (int i = tid; i < H; i += NTM) op_lds[i] = in.d_h0[i];
  __syncthreads();

  int dead = 0;
  // exact f32 op recurrence state held by tid<3 (same thread every step)
  float opreg = (tid < 3) ? in.d_h0[c0g3 + tid] : 0.f;

  for (int g = 0; g < GG; g++) {
    int s = g & 127, b = g >> 7;
    int g1 = g + 1, s1 = g1 & 127;
    int spk_cur = in.speaker_info[in.chat_ids[b] * SS + s];
    int spk_next = (g1 < GG) ? in.speaker_info[in.chat_ids[g1 >> 7] * SS + s1] : 0;
    float cv = w.cvec[g];
    if (tid < 18) loc_gis[tid] = w.GIS[(long)g * H6 + rrS(tid)];

    // ---- PH1: 1 tag per thread ----
    int bail = 0;
    if (!dead) {
      if (g > 0 && tid < 256) {
        u64 v = poll48(w.op_tag + tid, g, bail);
        op_lds[3 * tid]     = bf2f((uint32)(v & 0xffffu));
        op_lds[3 * tid + 1] = bf2f((uint32)((v >> 16) & 0xffffu));
        op_lds[3 * tid + 2] = bf2f((uint32)((v >> 32) & 0xffffu));
      } else if (tid >= 384 && s >= 1) {
        int j = tid - 384;
        if (j <= s - 2)
          el[j] = expf(fminf(pollf(w.sc_tag + (size_t)(g & 1) * SS + j, g, bail), 30.f));
      }
    }
    dead |= __syncthreads_or(bail);  // A

    if (s >= 1) {
      // ---- fused stage: every wave self-contained ----
      float2 xr[6];
      loadx_lds<6>(xr, op_lds);
      float a = 0.f;
      {
        const uint32* Ub = w.U_bf + (long)g * (H / 2);
        #pragma unroll
        for (int i = 0; i < 6; i++) {
          uint32 u = Ub[i * 64 + l];
          int idx = 2 * (i * 64 + l);
          a = fmaf(op_lds[idx], __uint_as_float(u << 16),
              fmaf(op_lds[idx + 1], __uint_as_float(u & 0xffff0000u), a));
        }
        a = xreduce(a);
      }
      float e1 = expf(fminf(a + cv, 30.f));
      float bs = 0.f;
      if (l <= s - 2) bs = el[l];
      if (l + 64 <= s - 2) bs += el[l + 64];
      bs = xreduce(bs);
      float suinv = 1.f / (e1 + bs + expf(fminf(cv, 30.f)));

      for (int r = wv; r < 36; r += 8) {
        if (r < 18) {
          float nr = dotr<6>(wMs + r * H, xr);
          float aa = 0.f;
          if (l <= s - 2) aa = el[l] * OPMSl[l * 19 + r];
          if (l + 64 <= s - 2) aa = fmaf(el[l + 64], OPMSl[(l + 64) * 19 + r], aa);
          #pragma unroll
          for (int o = 32; o > 0; o >>= 1) aa += __shfl_down(aa, o);
          if (l == 0) {
            OPMSl[(s - 1) * 19 + r] = nr;
            loc_si[r] = (aa + e1 * nr) * suinv + w.cvs[rrS(r)];
          }
        } else if (r < 27) {
          int t = r - 18;
          float nr = dotr<6>(wMg + t * H, xr);
          float aa = 0.f;
          if (l <= s - 2) aa = el[l] * OPMGl[l * 9 + t];
          if (l + 64 <= s - 2) aa = fmaf(el[l + 64], OPMGl[(l + 64) * 9 + t], aa);
          #pragma unroll
          for (int o = 32; o > 0; o >>= 1) aa += __shfl_down(aa, o);
          if (l == 0) {
            OPMGl[(s - 1) * 9 + t] = nr;
            loc_gw[t] = (aa + e1 * nr) * suinv + w.cvg[rrG(t)];
          }
        } else {
          int t = r - 27;
          float v = dotr<6>(wGhh + t * H, xr);
          if (l == 0) loc_ghg[t] = v + in.g_bhh[rrG(t)];
        }
      }
      if (g1 < GG && s1 != 0 && spk_next != spk_cur) {
        float2 xs[12];
        loadx_atm<12>(xs, w.sp_global + (long)spk_next * H2);
        for (int t = wv; t < 18; t += 8) {
          float v = dotr<12>(wShh + t * H2, xs);
          if (l == 0) loc_ghs[(g1 & 1) * 18 + t] = v + in.s_bhh[rrS(t)];
        }
      }
      if (wv == 7 && g1 < GG && s1 >= 2 && wg < s) {
        const float* opr = w.op_buf + (long)wg * H;
        const uint32* Ub1 = w.U_bf + (long)g1 * (H / 2);
        float a2 = 0.f;
        #pragma unroll
        for (int i0 = 0; i0 < 6; i0++) {
          int idx = i0 * 64 + l;
          float2 xa = ald2(opr + 2 * idx);
          uint32 u = Ub1[idx];
          a2 = fmaf(xa.x, __uint_as_float(u << 16),
               fmaf(xa.y, __uint_as_float(u & 0xffff0000u), a2));
        }
        #pragma unroll
        for (int o = 32; o > 0; o >>= 1) a2 += __shfl_down(a2, o);
        if (l == 0) ast64(w.sc_tag + (size_t)(g1 & 1) * SS + wg, tagf(g1, a2 + w.cvec[g1]));
      }
      if (wg == 0 && wv == 6) {
        int j = l;
        float pv = (j <= s - 2) ? el[j] * suinv : ((j == s - 1) ? e1 * suinv : 0.f);
        w.probs_buf[(long)g * SS + j] = pv;
        j = l + 64;
        pv = (j <= s - 2) ? el[j] * suinv : ((j == s - 1) ? e1 * suinv : 0.f);
        w.probs_buf[(long)g * SS + j] = pv;
      }
      __syncthreads();  // D
    } else {
      // s == 0: batch start
      if (tid < 18) loc_si[tid] = w.ch0s[rrS(tid)];
      else if (tid >= 32 && tid < 41) loc_gw[tid - 32] = w.chg0[rrG(tid - 32)];
      if (tid >= 64 && tid < 112) { int x = (tid - 64) / 6, t2 = (tid - 64) % 6; spc[x * 6 + t2] = in.h0[c0s + t2]; }
      if (tid >= 128 && tid < 176) {
        int x = (tid - 128) / 6, t2 = (tid - 128) % 6;
        if (x != spk_cur) ast(w.sp_global + (long)x * H2 + c0s + t2, in.h0[c0s + t2]);
      }
      if (wv == 3) {
        float2 xr[6];
        loadx_lds<6>(xr, op_lds);
        for (int j = 0; j < 9; j++) {
          float val = dotr<6>(wGhh + j * H, xr);
          if (l == 0) loc_ghg[j] = val + in.g_bhh[rrG(j)];
        }
      }
      if (wg == 0 && tid >= 384) w.probs_buf[(long)g * SS + (tid - 384)] = 0.f;
      __syncthreads();  // D
    }

    // ---- s-gate: own 6 output cols; pack to 2 h-tags via shfl ----
    float hn_val = 0.f;
    if (tid < 6) {
      int c = c0s + tid;
      float hprev = spc[spk_cur * 6 + tid];
      float ghr, ghz, ghn;
      if (s == 0) { ghr = w.ghs0[c]; ghz = w.ghs0[H2 + c]; ghn = w.ghs0[2 * H2 + c]; }
      else { const float* gb = loc_ghs + (g & 1) * 18; ghr = gb[tid]; ghz = gb[6 + tid]; ghn = gb[12 + tid]; }
      float gir = loc_gis[tid] + loc_si[tid];
      float giz = loc_gis[6 + tid] + loc_si[6 + tid];
      float gin = loc_gis[12 + tid] + loc_si[12 + tid];
      float r = sigm(gir + ghr), z = sigm(giz + ghz);
      float n = tanhf(gin + r * ghn);
      float hn = (1.f - z) * n + z * hprev;
      spc[spk_cur * 6 + tid] = hn;
      ast(w.sp_global + (long)spk_cur * H2 + c, hn);
      w.h_buf[(long)g * H2 + c] = hn;
      hn_val = hn;
    }
    if (wv == 0) {
      float p0 = __shfl(hn_val, 0), p1 = __shfl(hn_val, 1), p2 = __shfl(hn_val, 2);
      float p3 = __shfl(hn_val, 3), p4 = __shfl(hn_val, 4), p5 = __shfl(hn_val, 5);
      if (l == 0) ast64(w.h_tag + 2 * wg, tag3(g1, p0, p1, p2));
      else if (l == 1) ast64(w.h_tag + 2 * wg + 1, tag3(g1, p3, p4, p5));
    }

    // ---- PH2: 1 h-tag per thread ----
    if (tid < 9) loc_gig[tid] = w.GIG[(long)g * H3 + rrG(tid)];
    bail = 0;
    if (!dead) {
      u64 v = poll48(w.h_tag + tid, g1, bail);
      h_lds[3 * tid]     = bf2f((uint32)(v & 0xffffu));
      h_lds[3 * tid + 1] = bf2f((uint32)((v >> 16) & 0xffffu));
      h_lds[3 * tid + 2] = bf2f((uint32)((v >> 32) & 0xffffu));
    }
    dead |= __syncthreads_or(bail);  // E

    {
      int needsh = (g1 < GG && s1 != 0 && (spk_next == spk_cur || s == 0)) ? 1 : 0;
      int diff = (spk_next != spk_cur);
      if (needsh) {
        float2 xs[12];
        if (diff) loadx_atm<12>(xs, w.sp_global + (long)spk_next * H2);
        else loadx_lds<12>(xs, h_lds);
        for (int t = wv; t < 18; t += 8) {
          float val = dotr<12>(wShh + t * H2, xs);
          if (l == 0) loc_ghs[(g1 & 1) * 18 + t] = val + in.s_bhh[rrS(t)];
        }
      }
      {
        float2 xh[12];
        loadx_lds<12>(xh, h_lds);
        for (int t = wv; t < 9; t += 8) {
          float val = dotr<12>(wGab + t * H2, xh);
          if (l == 0) loc_gih[t] = val;
        }
      }
    }
    __syncthreads();  // F

    // ---- op-gate: tid<3, exact f32 recurrence; wave-0 packs the tag ----
    if (tid < 3) {
      int c = c0g3 + tid;
      float gir = loc_gig[tid]     + loc_gw[tid]     + loc_gih[tid];
      float giz = loc_gig[3 + tid] + loc_gw[3 + tid] + loc_gih[3 + tid];
      float gin = loc_gig[6 + tid] + loc_gw[6 + tid] + loc_gih[6 + tid];
      float r = sigm(gir + loc_ghg[tid]);
      float z = sigm(giz + loc_ghg[3 + tid]);
      float n = tanhf(gin + r * loc_ghg[6 + tid]);
      float o = (1.f - z) * n + z * opreg;
      opreg = o;
      ast(w.op_buf + (long)s * H + c, o);
      w.out_op[(long)g * H + c] = o;
    }
    if (wv == 0) {
      float o0 = __shfl(opreg, 0), o1 = __shfl(opreg, 1), o2 = __shfl(opreg, 2);
      asm volatile("s_waitcnt vmcnt(0)" ::: "memory");
      if (l == 0) ast64(w.op_tag + wg, tag3(g1, o0, o1, o2));
    }
  }
}

// ================= epilogue =================

__global__ __launch_bounds__(NT) void fixup_u_k(WS w) {
  long i = (long)blockIdx.x * NT + threadIdx.x;
  if (i < (long)GG * H) {
    int m = (int)(i % H);
    w.U[i] = (w.U[i] + w.cu[m]) * INVSCALE;
  }
}

__global__ __launch_bounds__(NT) void cvec_k(WS w) {
  int g = blockIdx.x * 4 + (threadIdx.x >> 6);
  int l = threadIdx.x & 63;
  const float* d = w.dialogue + (long)g * H;
  float p = 0.f;
  for (int i = l; i < H; i += 64) p = fmaf(d[i], w.vkq[i], p);
  #pragma unroll
  for (int o = 32; o > 0; o >>= 1) p += __shfl_down(p, o);
  if (l == 0) w.cvec[g] = (p + w.cb[0]) * INVSCALE;
}

__global__ __launch_bounds__(NT) void epi_W_k(WS w) {
  int g = blockIdx.x, b = g >> 7;
  __shared__ float pl[SS];
  if (threadIdx.x < SS) pl[threadIdx.x] = w.probs_buf[(long)g * SS + threadIdx.x];
  __syncthreads();
  const float* opb = w.out_op + (long)b * SS * H;
  for (int n = threadIdx.x; n < H; n += NT) {
    float acc = 0.f;
    for (int j = 0; j < SS; j++) acc = fmaf(pl[j], opb[(long)j * H + n], acc);
    w.Wbuf[(long)g * H + n] = acc;
  }
}

__global__ __launch_bounds__(NT) void assemble_k(IN in, WS w) {
  long idx = (long)blockIdx.x * NT + threadIdx.x;
  if (idx >= (long)GG * H2) return;
  long g = idx / H2;
  int k = (int)(idx - g * H2);
  int s = (int)(g & 127);
  float t;
  if (k < H) t = (s == 0) ? in.attn_h[k] : w.AO[g * H + k];
  else t = w.dialogue[g * H + (k - H)];
  w.out_spop[idx] = w.h_buf[idx] + t;
}

// ================= host =================

extern "C" void kernel_launch(void* const* d_in, const int* in_sizes, int n_in,
                              void* d_out, int out_size, void* d_ws, size_t ws_size,
                              hipStream_t stream) {
  IN in;
  in.chat_ids = (const int*)d_in[0];
  in.speaker_info = (const int*)d_in[1];
  in.inputs = (const int*)d_in[4];
  in.emb = (const float*)d_in[5];
  in.d_wih = (const float*)d_in[6];  in.d_whh = (const float*)d_in[7];
  in.d_bih = (const float*)d_in[8];  in.d_bhh = (const float*)d_in[9];
  in.g_wih = (const float*)d_in[10]; in.g_whh = (const float*)d_in[11];
  in.g_bih = (const float*)d_in[12]; in.g_bhh = (const float*)d_in[13];
  in.s_wih = (const float*)d_in[14]; in.s_whh = (const float*)d_in[15];
  in.s_bih = (const float*)d_in[16]; in.s_bhh = (const float*)d_in[17];
  in.wq = (const float*)d_in[18];  in.bq = (const float*)d_in[19];
  in.wk = (const float*)d_in[20];  in.bk = (const float*)d_in[21];
  in.wv = (const float*)d_in[22];  in.bv = (const float*)d_in[23];
  in.h0 = (const float*)d_in[24];  in.d_h0 = (const float*)d_in[25];
  in.attn_h = (const float*)d_in[26];

  char* base = (char*)d_ws;
  size_t off = 0;
  auto A = [&](size_t bytes) -> void* {
    size_t r = (off + 255) & ~(size_t)255;
    off = r + bytes;
    return (void*)(base + r);
  };
  WS w;
  w.flags1 = (int*)A(NWG * 16 * 4);
  w.Mqk = (float*)A((size_t)H * H * 4);
  w.Gsum = (float*)A((size_t)H3 * H * 4);
  w.cu = (float*)A(H * 4);
  w.vkq = (float*)A(H * 4);
  w.cb = (float*)A(4);
  w.cvs = (float*)A(H6 * 4);
  w.ch0s = (float*)A(H6 * 4);
  w.cvg = (float*)A(H3 * 4);
  w.chg0 = (float*)A(H3 * 4);
  w.ghs0 = (float*)A(H6 * 4);
  w.Ms = (float*)A((size_t)H6 * H * 4);
  w.Mg = (float*)A((size_t)H3 * H * 4);
  {
    void* r1 = A((size_t)GG * H6 * 4);  // max(gi_d [GG*H3], GIS [GG*H6])
    w.gi_d = (float*)r1;
    w.GIS = (float*)r1;
  }
  w.gi_bf = (uint32*)A((size_t)GG * H3 * 2);
  w.U_bf = (uint32*)A((size_t)GG * H * 2);
  w.dialogue = (float*)A((size_t)GG * H * 4);
  w.U = (float*)A((size_t)GG * H * 4);
  w.cvec = (float*)A(GG * 4);
  w.GIG = (float*)A((size_t)GG * H3 * 4);
  w.gh_dbuf = (float*)A((size_t)2 * BB * H3 * 4);
  w.sp_global = (float*)A((size_t)BB * H2 * 4);
  w.op_buf = (float*)A((size_t)SS * H * 4);
  w.op_tag = (u64*)A((size_t)NWG * 8);
  w.h_tag = (u64*)A((size_t)2 * NWG * 8);
  w.sc_tag = (u64*)A((size_t)2 * SS * 8);
  w.probs_buf = (float*)A((size_t)GG * SS * 4);
  w.h_buf = (float*)A((size_t)GG * H2 * 4);
  w.Wbuf = (float*)A((size_t)GG * H * 4);
  w.AO = (float*)A((size_t)GG * H * 4);
  w.out_op = (float*)d_out;
  w.out_spop = (float*)d_out + (size_t)GG * H;

  (void)hipFuncSetAttribute((const void*)coop_main, hipFuncAttributeMaxDynamicSharedMemorySize, DYN_LDS);

  (void)hipMemsetAsync(w.flags1, 0, NWG * 16 * 4, stream);
  (void)hipMemsetAsync(w.op_tag, 0, (size_t)NWG * 8, stream);
  (void)hipMemsetAsync(w.h_tag, 0, (size_t)2 * NWG * 8, stream);
  (void)hipMemsetAsync(w.sc_tag, 0, (size_t)2 * SS * 8, stream);

  const long NG = (long)H3 * H;
  prep1_k<<<(int)((NG + 2 * H + 1 + NT - 1) / NT), NT, 0, stream>>>(in, w);
  prep2_k<<<(H6 + H3 + H6 + 3) / 4, NT, 0, stream>>>(in, w);

  // Mqk = wq^T @ wk
  gemm_k<<<dim3(H / 64, H / 64), NT, 0, stream>>>(in.wq, 1, H, in.wk, H, w.Mqk, H, H, H);
  // Ms = s_wihA @ wv ; Mg = g_wihA @ wv
  mgemm_k<<<dim3(H / 128, H6 / 128), NT, 0, stream>>>(in.s_wih, H2, nullptr, in.wv, H, 0, nullptr, w.Ms, H, H);
  mgemm_k<<<dim3(H / 128, H3 / 128), NT, 0, stream>>>(in.g_wih, H3, nullptr, in.wv, H, 0, nullptr, w.Mg, H, H);
  // gi_d = emb[inputs] @ d_wih^T + d_bih, then pack to bf16x2
  mgemm_k<<<dim3(H3 / 128, GG / 128), NT, 0, stream>>>(in.emb, H, in.inputs, in.d_wih, H, 1, in.d_bih, w.gi_d, H3, H);
  pack_k<<<(int)(((long)GG * H3 / 2 + NT - 1) / NT), NT, 0, stream>>>(w.gi_d, w.gi_bf, (long)GG * H3 / 2);
  coop_rnnD<<<NWG, NTM, 0, stream>>>(in, w);

  // U = dialogue @ Mqk ; GIS = dialogue @ s_wihB^T + s_bih ; GIG = dialogue @ Gsum^T + g_bih
  mgemm_k<<<dim3(H / 128, GG / 128), NT, 0, stream>>>(w.dialogue, H, nullptr, w.Mqk, H, 0, nullptr, w.U, H, H);
  mgemm_k<<<dim3(H6 / 128, GG / 128), NT, 0, stream>>>(w.dialogue, H, nullptr, in.s_wih + H, H2, 1, in.s_bih, w.GIS, H6, H);
  mgemm_k<<<dim3(H3 / 128, GG / 128), NT, 0, stream>>>(w.dialogue, H, nullptr, w.Gsum, H, 1, in.g_bih, w.GIG, H3, H);
  fixup_u_k<<<(GG * H + NT - 1) / NT, NT, 0, stream>>>(w);
  pack_k<<<(int)(((long)GG * H / 2 + NT - 1) / NT), NT, 0, stream>>>(w.U, w.U_bf, (long)GG * H / 2);
  cvec_k<<<GG / 4, NT, 0, stream>>>(w);

  coop_main<<<NWG, NTM, DYN_LDS, stream>>>(in, w);

  epi_W_k<<<GG, NT, 0, stream>>>(w);
  // AO = Wbuf @ wv^T + bv
  mgemm_k<<<dim3(H / 128, GG / 128), NT, 0, stream>>>(w.Wbuf, H, nullptr, in.wv, H, 1, in.bv, w.AO, H, H);
  assemble_k<<<(int)(((long)GG * H2 + NT - 1) / NT), NT, 0, stream>>>(in, w);
}

// Round 16
// 13762.538 us; speedup vs baseline: 1.2712x; 1.1543x over previous
//
#include <hip/hip_runtime.h>
#include <hip/hip_bf16.h>

typedef unsigned int uint32;
typedef unsigned short u16;
typedef unsigned long long u64;
typedef __attribute__((ext_vector_type(8))) short s16x8;
typedef __attribute__((ext_vector_type(4))) float f32x4;

#define H    768
#define H2   1536
#define H3   2304
#define H6   4608
#define BB   8
#define SS   128
#define GG   1024
#define NWG  256
#define NT   256
#define NTM  512
#define INVSCALE 0.036084391824351615f
#define SPIN_LIMIT (1 << 17)
#define DYN_LDS 163200

struct IN {
  const int *chat_ids, *speaker_info, *inputs;
  const float *emb, *d_wih, *d_whh, *d_bih, *d_bhh;
  const float *g_wih, *g_whh, *g_bih, *g_bhh;
  const float *s_wih, *s_whh, *s_bih, *s_bhh;
  const float *wq, *bq, *wk, *bk, *wv, *bv;
  const float *h0, *d_h0, *attn_h;
};

struct WS {
  int *flags1;
  float *Mqk, *Gsum;
  float *cu, *vkq, *cb, *cvs, *ch0s, *cvg, *chg0, *ghs0;
  float *Ms, *Mg;
  float *gi_d, *GIS;           // aliased region
  uint32 *gi_bf, *U_bf;        // bf16x2-packed copies
  float *dialogue, *U, *cvec, *GIG;
  float *gh_dbuf;              // [2][BB][H3]
  float *sp_global;            // [8][H2]
  float *op_buf;               // [SS][H]
  u64 *op_tag;                 // [H]   epoch-tagged op broadcast
  u64 *h_tag;                  // [H2]  epoch-tagged h broadcast
  u64 *sc_tag;                 // [2][SS] epoch-tagged scores (parity dbuf)
  float *probs_buf;
  float *h_buf, *Wbuf, *AO;
  float *out_op, *out_spop;
};

__device__ inline float sigm(float x) { return 1.f / (1.f + expf(-x)); }

__device__ inline u16 f2bf(float v) {
  __hip_bfloat16 b = __float2bfloat16(v);
  return *reinterpret_cast<u16*>(&b);
}
__device__ inline uint32 pack2bf(float a, float b) {
  return (uint32)f2bf(a) | ((uint32)f2bf(b) << 16);
}

// ---- agent-scope write-through accessors ----
__device__ inline float2 ld2(const float* p) { return *(const float2*)p; }
__device__ inline float2 ald2(const float* p) {
  u64 v = __hip_atomic_load((const u64*)p, __ATOMIC_RELAXED, __HIP_MEMORY_SCOPE_AGENT);
  union { u64 u; float2 f; } c; c.u = v; return c.f;
}
__device__ inline float ald(const float* p) {
  return __hip_atomic_load(p, __ATOMIC_RELAXED, __HIP_MEMORY_SCOPE_AGENT);
}
__device__ inline void ast(float* p, float v) {
  __hip_atomic_store(p, v, __ATOMIC_RELAXED, __HIP_MEMORY_SCOPE_AGENT);
}
__device__ inline void ast64(u64* p, u64 v) {
  __hip_atomic_store(p, v, __ATOMIC_RELAXED, __HIP_MEMORY_SCOPE_AGENT);
}
__device__ inline u64 ald64(const u64* p) {
  return __hip_atomic_load(p, __ATOMIC_RELAXED, __HIP_MEMORY_SCOPE_AGENT);
}
__device__ inline u64 tagf(int ep, float v) {
  return ((u64)(uint32)ep << 32) | (u64)__float_as_uint(v);
}

// single-tag poll — tight loop (paced by the load RT itself)
__device__ inline float pollf(const u64* p, int ep, int& bail) {
  int spins = 0;
  u64 v;
  for (;;) {
    v = ald64(p);
    if ((int)(v >> 32) >= ep) break;
    if (++spins > SPIN_LIMIT) { bail = 1; break; }
  }
  return __uint_as_float((uint32)v);
}

// ---- flat grid barrier for rnnD: flags spread one per 64B line; tight poll ----
__device__ inline void gbar2(int* flags, int epoch, int& dead) {
  int bail = 0;
  __syncthreads();
  if (!dead) {
    if (threadIdx.x == 0)
      __hip_atomic_store(&flags[blockIdx.x * 16], epoch, __ATOMIC_RELAXED, __HIP_MEMORY_SCOPE_AGENT);
    if (threadIdx.x < NWG) {
      int spins = 0;
      while (__hip_atomic_load(&flags[threadIdx.x * 16], __ATOMIC_RELAXED, __HIP_MEMORY_SCOPE_AGENT) < epoch) {
        if (++spins > SPIN_LIMIT) { bail = 1; break; }
      }
    }
  }
  dead |= __syncthreads_or(bail);
  asm volatile("" ::: "memory");
}

// ---- register-x dot helpers ----
template <int NI>
__device__ inline float dotr(const u16* wcol, const float2* xr) {
  const uint32* wp = (const uint32*)wcol;
  int l = threadIdx.x & 63;
  float acc = 0.f;
  #pragma unroll
  for (int i = 0; i < NI; i++) {
    uint32 u = wp[i * 64 + l];
    acc = fmaf(xr[i].x, __uint_as_float(u << 16),
          fmaf(xr[i].y, __uint_as_float(u & 0xffff0000u), acc));
  }
  #pragma unroll
  for (int o = 32; o > 0; o >>= 1) acc += __shfl_down(acc, o);
  return acc;  // valid on lane 0
}
__device__ inline float xreduce(float a) {
  #pragma unroll
  for (int o = 32; o > 0; o >>= 1) a += __shfl_xor(a, o);
  return a;  // valid on all lanes
}
template <int NI>
__device__ inline void loadx_lds(float2* xr, const float* x) {
  int l = threadIdx.x & 63;
  #pragma unroll
  for (int i = 0; i < NI; i++) xr[i] = ld2(x + 2 * (i * 64 + l));
}
template <int NI>
__device__ inline void loadx_atm(float2* xr, const float* x) {
  int l = threadIdx.x & 63;
  #pragma unroll
  for (int i = 0; i < NI; i++) xr[i] = ald2(x + 2 * (i * 64 + l));
}

// ================= prep kernels =================

__global__ __launch_bounds__(NT) void prep1_k(IN in, WS w) {
  long i = (long)blockIdx.x * NT + threadIdx.x;
  const long NG = (long)H3 * H;
  if (i < NG) {
    long n = i / H, k = i - n * H;
    w.Gsum[i] = in.g_wih[n * H3 + H + k] + in.g_wih[n * H3 + 2 * H + k];
  } else if (i < NG + H) {
    int m = (int)(i - NG);
    float a = 0.f;
    for (int t = 0; t < H; t++) a = fmaf(in.bq[t], in.wk[(long)t * H + m], a);
    w.cu[m] = a;
  } else if (i < NG + 2 * H) {
    int m = (int)(i - NG - H);
    float a = 0.f;
    for (int t = 0; t < H; t++) a = fmaf(in.bk[t], in.wq[(long)t * H + m], a);
    w.vkq[m] = a;
  } else if (i == NG + 2 * H) {
    float a = 0.f;
    for (int t = 0; t < H; t++) a = fmaf(in.bk[t], in.bq[t], a);
    w.cb[0] = a;
  }
}

__global__ __launch_bounds__(NT) void prep2_k(IN in, WS w) {
  int wid = blockIdx.x * (NT / 64) + (threadIdx.x >> 6);
  int l = threadIdx.x & 63;
  const int R1 = H6, R2 = H6 + H3, R3 = H6 + H3 + H6;
  if (wid < R1) {
    const float* row = in.s_wih + (long)wid * H2;
    float a = 0.f, c = 0.f;
    for (int i = l; i < H; i += 64) { float rv = row[i]; a = fmaf(in.bv[i], rv, a); c = fmaf(in.attn_h[i], rv, c); }
    #pragma unroll
    for (int o = 32; o > 0; o >>= 1) { a += __shfl_down(a, o); c += __shfl_down(c, o); }
    if (l == 0) { w.cvs[wid] = a; w.ch0s[wid] = c; }
  } else if (wid < R2) {
    int k = wid - R1;
    const float* row = in.g_wih + (long)k * H3;
    float a = 0.f, c = 0.f;
    for (int i = l; i < H; i += 64) { float rv = row[i]; a = fmaf(in.bv[i], rv, a); c = fmaf(in.attn_h[i], rv, c); }
    #pragma unroll
    for (int o = 32; o > 0; o >>= 1) { a += __shfl_down(a, o); c += __shfl_down(c, o); }
    if (l == 0) { w.cvg[k] = a; w.chg0[k] = c; }
  } else if (wid < R3) {
    int k = wid - R2;
    const float* row = in.s_whh + (long)k * H2;
    float a = 0.f;
    for (int i = l; i < H2; i += 64) a = fmaf(in.h0[i], row[i], a);
    #pragma unroll
    for (int o = 32; o > 0; o >>= 1) a += __shfl_down(a, o);
    if (l == 0) w.ghs0[k] = a + in.s_bhh[k];
  }
}

__global__ __launch_bounds__(NT) void pack_k(const float* src, uint32* dst, long n2) {
  long i = (long)blockIdx.x * NT + threadIdx.x;
  if (i < n2) dst[i] = pack2bf(src[2 * i], src[2 * i + 1]);
}

// ---- f32 GEMM (kept only for Mqk: col-major A) ----
__global__ __launch_bounds__(NT) void gemm_k(const float* A, long sAm, long sAk,
                                             const float* B, long sBk,
                                             float* C, int M, int N, int K) {
  __shared__ float As[16][65];
  __shared__ float Bs[16][65];
  int m0 = blockIdx.y * 64, n0 = blockIdx.x * 64;
  int tid = threadIdx.x;
  int tx = tid & 15, ty = tid >> 4;
  float acc[4][4] = {};
  for (int k0 = 0; k0 < K; k0 += 16) {
    {
      int m = tid & 63, kb = tid >> 6;
      for (int p = 0; p < 4; p++) {
        int k = kb + p * 4;
        As[k][m] = A[(long)(m0 + m) * sAm + (long)(k0 + k) * sAk];
      }
    }
    {
      int n = tid & 63, kb = tid >> 6;
      for (int p = 0; p < 4; p++) {
        int k = kb + p * 4;
        Bs[k][n] = B[(long)(k0 + k) * sBk + (n0 + n)];
      }
    }
    __syncthreads();
    #pragma unroll
    for (int k = 0; k < 16; k++) {
      float a[4], b[4];
      #pragma unroll
      for (int i = 0; i < 4; i++) a[i] = As[k][ty * 4 + i];
      #pragma unroll
      for (int j = 0; j < 4; j++) b[j] = Bs[k][tx * 4 + j];
      #pragma unroll
      for (int i = 0; i < 4; i++)
        #pragma unroll
        for (int j = 0; j < 4; j++) acc[i][j] = fmaf(a[i], b[j], acc[i][j]);
    }
    __syncthreads();
  }
  for (int i = 0; i < 4; i++)
    for (int j = 0; j < 4; j++) {
      int m = m0 + ty * 4 + i, n = n0 + tx * 4 + j;
      C[(long)m * N + n] = acc[i][j];
    }
}

// ---- MFMA bf16 GEMM ----
__global__ __launch_bounds__(NT) void mgemm_k(const float* A, long sAm, const int* gather,
                                              const float* B, long sB, int bColMajor,
                                              const float* bias, float* C, int N, int K) {
  __shared__ u16 Al[128 * 40];
  __shared__ u16 Bl[128 * 40];
  int tid = threadIdx.x;
  int n0 = blockIdx.x * 128, m0 = blockIdx.y * 128;
  int l = tid & 63, wv = tid >> 6;
  int wr = wv >> 1, wc = wv & 1;
  f32x4 acc[4][4] = {};
  long arow = gather ? (long)gather[m0 + (tid >> 1)] : (long)(m0 + (tid >> 1));
  for (int k0 = 0; k0 < K; k0 += 32) {
    __syncthreads();
    {
      int r = tid >> 1, half = tid & 1;
      const float* src = A + arow * sAm + k0 + half * 16;
      uint32* dst = (uint32*)(Al + r * 40 + half * 16);
      #pragma unroll
      for (int j = 0; j < 8; j++) dst[j] = pack2bf(src[2 * j], src[2 * j + 1]);
    }
    if (bColMajor) {
      int n = tid >> 1, half = tid & 1;
      const float* src = B + (long)(n0 + n) * sB + k0 + half * 16;
      uint32* dst = (uint32*)(Bl + n * 40 + half * 16);
      #pragma unroll
      for (int j = 0; j < 8; j++) dst[j] = pack2bf(src[2 * j], src[2 * j + 1]);
    } else {
      int kk = tid & 31, nb = tid >> 5;
      const float* src = B + (long)(k0 + kk) * sB + n0 + nb * 16;
      #pragma unroll
      for (int j = 0; j < 16; j++) Bl[(nb * 16 + j) * 40 + kk] = f2bf(src[j]);
    }
    __syncthreads();
    s16x8 af[4], bf[4];
    #pragma unroll
    for (int i = 0; i < 4; i++) {
      af[i] = *(const s16x8*)(Al + (wr * 64 + i * 16 + (l & 15)) * 40 + (l >> 4) * 8);
      bf[i] = *(const s16x8*)(Bl + (wc * 64 + i * 16 + (l & 15)) * 40 + (l >> 4) * 8);
    }
    #pragma unroll
    for (int i = 0; i < 4; i++)
      #pragma unroll
      for (int j = 0; j < 4; j++)
        acc[i][j] = __builtin_amdgcn_mfma_f32_16x16x32_bf16(af[i], bf[j], acc[i][j], 0, 0, 0);
  }
  #pragma unroll
  for (int i = 0; i < 4; i++)
    #pragma unroll
    for (int j = 0; j < 4; j++) {
      int n = n0 + wc * 64 + j * 16 + (l & 15);
      int mb = m0 + wr * 64 + i * 16 + ((l >> 4) << 2);
      float bb = bias ? bias[n] : 0.f;
      #pragma unroll
      for (int r = 0; r < 4; r++)
        C[(long)(mb + r) * N + n] = acc[i][j][r] + bb;
    }
}

// ================= sequential kernels =================

__global__ __launch_bounds__(NTM) void coop_rnnD(IN in, WS w) {
  __shared__ u16 wD[9 * H];
  __shared__ float hB[BB][H];
  int tid = threadIdx.x, wg = blockIdx.x;
  int c0 = wg * 9;
  int l = tid & 63, wv = tid >> 6;
  for (int i = tid; i < 9 * H; i += NTM)
    wD[i] = f2bf(in.d_whh[(long)(c0 + i / H) * H + (i % H)]);
  __syncthreads();
  int epoch = 1, dead = 0;
  for (int t = 0; t < SS; t++) {
    if (t > 0) {
      float* ghb = w.gh_dbuf + (size_t)(t & 1) * BB * H3;
      for (int tk = wv; tk < 72; tk += 8) {
        int b = tk / 9, j = tk - b * 9;
        float2 xr[6];
        loadx_lds<6>(xr, hB[b]);
        float val = dotr<6>(wD + j * H, xr);
        if (l == 0) ast(ghb + (long)b * H3 + c0 + j, val + in.d_bhh[c0 + j]);
      }
      gbar2(w.flags1, epoch++, dead);
    }
    const float* ghb = w.gh_dbuf + (size_t)(t & 1) * BB * H3;
    for (int pc = tid; pc < BB * H / 2; pc += NTM) {
      int b = pc / (H / 2), k = 2 * (pc - b * (H / 2));
      const uint32* gi = w.gi_bf + ((long)(b * SS + t)) * (H3 / 2);
      uint32 u0 = gi[k >> 1], u1 = gi[(H + k) >> 1], u2 = gi[(2 * H + k) >> 1];
      float gr0 = __uint_as_float(u0 << 16), gr1 = __uint_as_float(u0 & 0xffff0000u);
      float gz0 = __uint_as_float(u1 << 16), gz1 = __uint_as_float(u1 & 0xffff0000u);
      float gn0 = __uint_as_float(u2 << 16), gn1 = __uint_as_float(u2 & 0xffff0000u);
      float hr0, hr1, hz0, hz1, hn0, hn1;
      if (t == 0) {
        hr0 = in.d_bhh[k]; hr1 = in.d_bhh[k + 1];
        hz0 = in.d_bhh[H + k]; hz1 = in.d_bhh[H + k + 1];
        hn0 = in.d_bhh[2 * H + k]; hn1 = in.d_bhh[2 * H + k + 1];
      } else {
        const float* gb = ghb + (long)b * H3;
        float2 a0 = ald2(gb + k), a1 = ald2(gb + H + k), a2 = ald2(gb + 2 * H + k);
        hr0 = a0.x; hr1 = a0.y; hz0 = a1.x; hz1 = a1.y; hn0 = a2.x; hn1 = a2.y;
      }
      float p0 = (t == 0) ? 0.f : hB[b][k], p1 = (t == 0) ? 0.f : hB[b][k + 1];
      float r0 = sigm(gr0 + hr0), r1 = sigm(gr1 + hr1);
      float z0 = sigm(gz0 + hz0), z1 = sigm(gz1 + hz1);
      float n0 = tanhf(gn0 + r0 * hn0), n1 = tanhf(gn1 + r1 * hn1);
      float h0v = (1.f - z0) * n0 + z0 * p0, h1v = (1.f - z1) * n1 + z1 * p1;
      hB[b][k] = h0v; hB[b][k + 1] = h1v;
      if (wg == 0) *(float2*)(w.dialogue + ((long)(b * SS + t)) * H + k) = make_float2(h0v, h1v);
    }
    __syncthreads();
  }
}

// Distributed-gate main loop with fused tagged-data synchronization.
// WG owns g-cols [wg*3,+3), s-cols [wg*6,+6).
// PH1 fused: each wave self-contained; op-tag released BEFORE op_buf/out_op
// stores (ordering of those is transitively guaranteed: consumers read row wg
// >=2 steps later, after the producer's intervening __syncthreads vmcnt drains).
__global__ __launch_bounds__(NTM) void coop_main(IN in, WS w) {
  extern __shared__ char Lds[];
  u16*   wShh  = (u16*)(Lds + 0);        // [18][1536]
  u16*   wGab  = (u16*)(Lds + 55296);    // [9][1536]
  u16*   wMs   = (u16*)(Lds + 82944);    // [18][768]
  u16*   wMg   = (u16*)(Lds + 110592);   // [9][768]
  u16*   wGhh  = (u16*)(Lds + 124416);   // [9][768]
  float* OPMSl = (float*)(Lds + 138240); // [128][19]
  float* OPMGl = (float*)(Lds + 147968); // [128][9]
  float* h_lds = (float*)(Lds + 152576); // [1536]
  float* op_lds= (float*)(Lds + 158720); // [768]
  float* el    = (float*)(Lds + 161792); // [128]
  float* red   = (float*)(Lds + 162304); // [64] (unused)
  float* loc_si  = (float*)(Lds + 162560); // [18]
  float* loc_ghs = (float*)(Lds + 162632); // [2][18]
  float* loc_gw  = (float*)(Lds + 162776); // [9]
  float* loc_ghg = (float*)(Lds + 162812); // [9]
  float* loc_gih = (float*)(Lds + 162848); // [9]
  float* loc_gis = (float*)(Lds + 162884); // [18]
  float* loc_gig = (float*)(Lds + 162956); // [9]
  float* spc     = (float*)(Lds + 162992); // [8][6]

  int tid = threadIdx.x, wg = blockIdx.x;
  int l = tid & 63, wv = tid >> 6;
  int c0s = wg * 6, c0g3 = wg * 3;
  auto rrS = [&](int j) { return (j / 6) * H2 + c0s + (j % 6); };
  auto rrG = [&](int j) { return (j / 3) * H + c0g3 + (j % 3); };

  for (int i = tid; i < 18 * H2; i += NTM) { int j = i / H2, k = i - j * H2; wShh[i] = f2bf(in.s_whh[(long)rrS(j) * H2 + k]); }
  for (int i = tid; i < 9 * H2;  i += NTM) { int j = i / H2, k = i - j * H2; wGab[i] = f2bf(in.g_wih[(long)rrG(j) * H3 + k]); }
  for (int i = tid; i < 18 * H;  i += NTM) { int j = i / H,  k = i - j * H;  wMs[i]  = f2bf(w.Ms[(long)rrS(j) * H + k]); }
  for (int i = tid; i < 9 * H;   i += NTM) { int j = i / H,  k = i - j * H;  wMg[i]  = f2bf(w.Mg[(long)rrG(j) * H + k]); }
  for (int i = tid; i < 9 * H;   i += NTM) { int j = i / H,  k = i - j * H;  wGhh[i] = f2bf(in.g_whh[(long)rrG(j) * H + k]); }
  for (int i = tid; i < H; i += NTM) op_lds[i] = in.d_h0[i];
  __syncthreads();

  int dead = 0;

  for (int g = 0; g < GG; g++) {
    int s = g & 127, b = g >> 7;
    int g1 = g + 1, s1 = g1 & 127;
    int spk_cur = in.speaker_info[in.chat_ids[b] * SS + s];
    int spk_next = (g1 < GG) ? in.speaker_info[in.chat_ids[g1 >> 7] * SS + s1] : 0;
    float cv = w.cvec[g];
    if (tid < 18) loc_gis[tid] = w.GIS[(long)g * H6 + rrS(tid)];

    // ---- PH1: poll op tags (epoch g) + sc tags ----
    int bail = 0;
    if (!dead) {
      if (g > 0 && tid < 384) {
        int c = tid * 2;
        float v0 = pollf(w.op_tag + c, g, bail);
        float v1 = pollf(w.op_tag + c + 1, g, bail);
        op_lds[c] = v0; op_lds[c + 1] = v1;
      } else if (tid >= 384 && s >= 1) {
        int j = tid - 384;
        if (j <= s - 2)
          el[j] = expf(fminf(pollf(w.sc_tag + (size_t)(g & 1) * SS + j, g, bail), 30.f));
      }
    }
    dead |= __syncthreads_or(bail);  // A

    if (s >= 1) {
      // ---- fused stage: every wave self-contained ----
      float2 xr[6];
      loadx_lds<6>(xr, op_lds);
      float a = 0.f;
      {
        const uint32* Ub = w.U_bf + (long)g * (H / 2);
        #pragma unroll
        for (int i = 0; i < 6; i++) {
          uint32 u = Ub[i * 64 + l];
          int idx = 2 * (i * 64 + l);
          a = fmaf(op_lds[idx], __uint_as_float(u << 16),
              fmaf(op_lds[idx + 1], __uint_as_float(u & 0xffff0000u), a));
        }
        a = xreduce(a);
      }
      float e1 = expf(fminf(a + cv, 30.f));
      float bs = 0.f;
      if (l <= s - 2) bs = el[l];
      if (l + 64 <= s - 2) bs += el[l + 64];
      bs = xreduce(bs);
      float suinv = 1.f / (e1 + bs + expf(fminf(cv, 30.f)));

      for (int r = wv; r < 36; r += 8) {
        if (r < 18) {
          float nr = dotr<6>(wMs + r * H, xr);
          float aa = 0.f;
          if (l <= s - 2) aa = el[l] * OPMSl[l * 19 + r];
          if (l + 64 <= s - 2) aa = fmaf(el[l + 64], OPMSl[(l + 64) * 19 + r], aa);
          #pragma unroll
          for (int o = 32; o > 0; o >>= 1) aa += __shfl_down(aa, o);
          if (l == 0) {
            OPMSl[(s - 1) * 19 + r] = nr;
            loc_si[r] = (aa + e1 * nr) * suinv + w.cvs[rrS(r)];
          }
        } else if (r < 27) {
          int t = r - 18;
          float nr = dotr<6>(wMg + t * H, xr);
          float aa = 0.f;
          if (l <= s - 2) aa = el[l] * OPMGl[l * 9 + t];
          if (l + 64 <= s - 2) aa = fmaf(el[l + 64], OPMGl[(l + 64) * 9 + t], aa);
          #pragma unroll
          for (int o = 32; o > 0; o >>= 1) aa += __shfl_down(aa, o);
          if (l == 0) {
            OPMGl[(s - 1) * 9 + t] = nr;
            loc_gw[t] = (aa + e1 * nr) * suinv + w.cvg[rrG(t)];
          }
        } else {
          int t = r - 27;
          float v = dotr<6>(wGhh + t * H, xr);
          if (l == 0) loc_ghg[t] = v + in.g_bhh[rrG(t)];
        }
      }
      if (g1 < GG && s1 != 0 && spk_next != spk_cur) {
        float2 xs[12];
        loadx_atm<12>(xs, w.sp_global + (long)spk_next * H2);
        for (int t = wv; t < 18; t += 8) {
          float v = dotr<12>(wShh + t * H2, xs);
          if (l == 0) loc_ghs[(g1 & 1) * 18 + t] = v + in.s_bhh[rrS(t)];
        }
      }
      if (wv == 7 && g1 < GG && s1 >= 2 && wg < s) {
        const float* opr = w.op_buf + (long)wg * H;
        const uint32* Ub1 = w.U_bf + (long)g1 * (H / 2);
        float a2 = 0.f;
        #pragma unroll
        for (int i0 = 0; i0 < 6; i0++) {
          int idx = i0 * 64 + l;
          float2 xa = ald2(opr + 2 * idx);
          uint32 u = Ub1[idx];
          a2 = fmaf(xa.x, __uint_as_float(u << 16),
               fmaf(xa.y, __uint_as_float(u & 0xffff0000u), a2));
        }
        #pragma unroll
        for (int o = 32; o > 0; o >>= 1) a2 += __shfl_down(a2, o);
        if (l == 0) ast64(w.sc_tag + (size_t)(g1 & 1) * SS + wg, tagf(g1, a2 + w.cvec[g1]));
      }
      if (wg == 0 && wv == 6) {
        int j = l;
        float pv = (j <= s - 2) ? el[j] * suinv : ((j == s - 1) ? e1 * suinv : 0.f);
        w.probs_buf[(long)g * SS + j] = pv;
        j = l + 64;
        pv = (j <= s - 2) ? el[j] * suinv : ((j == s - 1) ? e1 * suinv : 0.f);
        w.probs_buf[(long)g * SS + j] = pv;
      }
      __syncthreads();  // D (single fused barrier)
    } else {
      // s == 0: batch start
      if (tid < 18) loc_si[tid] = w.ch0s[rrS(tid)];
      else if (tid >= 32 && tid < 41) loc_gw[tid - 32] = w.chg0[rrG(tid - 32)];
      if (tid >= 64 && tid < 112) { int x = (tid - 64) / 6, t2 = (tid - 64) % 6; spc[x * 6 + t2] = in.h0[c0s + t2]; }
      if (tid >= 128 && tid < 176) {
        int x = (tid - 128) / 6, t2 = (tid - 128) % 6;
        if (x != spk_cur) ast(w.sp_global + (long)x * H2 + c0s + t2, in.h0[c0s + t2]);
      }
      if (wv == 3) {
        float2 xr[6];
        loadx_lds<6>(xr, op_lds);
        for (int j = 0; j < 9; j++) {
          float val = dotr<6>(wGhh + j * H, xr);
          if (l == 0) loc_ghg[j] = val + in.g_bhh[rrG(j)];
        }
      }
      if (wg == 0 && tid >= 384) w.probs_buf[(long)g * SS + (tid - 384)] = 0.f;
      __syncthreads();  // D
    }

    // capture op_{g-1}[own col] into a register (op_lds rewritten next phase A)
    float op_prev = (tid < 3) ? op_lds[c0g3 + tid] : 0.f;

    // ---- s-gate: own 6 output cols; tag-store h (epoch g+1) FIRST ----
    if (tid < 6) {
      int c = c0s + tid;
      float hprev = spc[spk_cur * 6 + tid];
      float ghr, ghz, ghn;
      if (s == 0) { ghr = w.ghs0[c]; ghz = w.ghs0[H2 + c]; ghn = w.ghs0[2 * H2 + c]; }
      else { const float* gb = loc_ghs + (g & 1) * 18; ghr = gb[tid]; ghz = gb[6 + tid]; ghn = gb[12 + tid]; }
      float gir = loc_gis[tid] + loc_si[tid];
      float giz = loc_gis[6 + tid] + loc_si[6 + tid];
      float gin = loc_gis[12 + tid] + loc_si[12 + tid];
      float r = sigm(gir + ghr), z = sigm(giz + ghz);
      float n = tanhf(gin + r * ghn);
      float hn = (1.f - z) * n + z * hprev;
      spc[spk_cur * 6 + tid] = hn;
      ast64(w.h_tag + c, tagf(g1, hn));
      ast(w.sp_global + (long)spk_cur * H2 + c, hn);
      w.h_buf[(long)g * H2 + c] = hn;
    }

    // ---- PH2: poll h tags (epoch g+1) ----
    if (tid < 9) loc_gig[tid] = w.GIG[(long)g * H3 + rrG(tid)];
    bail = 0;
    if (!dead) {
      int c = tid * 3;
      float v0 = pollf(w.h_tag + c, g1, bail);
      float v1 = pollf(w.h_tag + c + 1, g1, bail);
      float v2 = pollf(w.h_tag + c + 2, g1, bail);
      h_lds[c] = v0; h_lds[c + 1] = v1; h_lds[c + 2] = v2;
    }
    dead |= __syncthreads_or(bail);  // E

    {
      int needsh = (g1 < GG && s1 != 0 && (spk_next == spk_cur || s == 0)) ? 1 : 0;
      int diff = (spk_next != spk_cur);
      if (needsh) {
        float2 xs[12];
        if (diff) loadx_atm<12>(xs, w.sp_global + (long)spk_next * H2);
        else loadx_lds<12>(xs, h_lds);
        for (int t = wv; t < 18; t += 8) {
          float val = dotr<12>(wShh + t * H2, xs);
          if (l == 0) loc_ghs[(g1 & 1) * 18 + t] = val + in.s_bhh[rrS(t)];
        }
      }
      {
        float2 xh[12];
        loadx_lds<12>(xh, h_lds);
        for (int t = wv; t < 9; t += 8) {
          float val = dotr<12>(wGab + t * H2, xh);
          if (l == 0) loc_gih[t] = val;
        }
      }
    }
    __syncthreads();  // F

    // ---- op-gate: own 3 cols; TAG RELEASED FIRST (no vmcnt on critical path) ----
    if (tid < 3) {
      int c = c0g3 + tid;
      float gir = loc_gig[tid]     + loc_gw[tid]     + loc_gih[tid];
      float giz = loc_gig[3 + tid] + loc_gw[3 + tid] + loc_gih[3 + tid];
      float gin = loc_gig[6 + tid] + loc_gw[6 + tid] + loc_gih[6 + tid];
      float r = sigm(gir + loc_ghg[tid]);
      float z = sigm(giz + loc_ghg[3 + tid]);
      float n = tanhf(gin + r * loc_ghg[6 + tid]);
      float o = (1.f - z) * n + z * op_prev;
      ast64(w.op_tag + c, tagf(g1, o));
      ast(w.op_buf + (long)s * H + c, o);
      w.out_op[(long)g * H + c] = o;
    }
  }
}

// ================= epilogue =================

__global__ __launch_bounds__(NT) void fixup_u_k(WS w) {
  long i = (long)blockIdx.x * NT + threadIdx.x;
  if (i < (long)GG * H) {
    int m = (int)(i % H);
    w.U[i] = (w.U[i] + w.cu[m]) * INVSCALE;
  }
}

__global__ __launch_bounds__(NT) void cvec_k(WS w) {
  int g = blockIdx.x * 4 + (threadIdx.x >> 6);
  int l = threadIdx.x & 63;
  const float* d = w.dialogue + (long)g * H;
  float p = 0.f;
  for (int i = l; i < H; i += 64) p = fmaf(d[i], w.vkq[i], p);
  #pragma unroll
  for (int o = 32; o > 0; o >>= 1) p += __shfl_down(p, o);
  if (l == 0) w.cvec[g] = (p + w.cb[0]) * INVSCALE;
}

__global__ __launch_bounds__(NT) void epi_W_k(WS w) {
  int g = blockIdx.x, b = g >> 7;
  __shared__ float pl[SS];
  if (threadIdx.x < SS) pl[threadIdx.x] = w.probs_buf[(long)g * SS + threadIdx.x];
  __syncthreads();
  const float* opb = w.out_op + (long)b * SS * H;
  for (int n = threadIdx.x; n < H; n += NT) {
    float acc = 0.f;
    for (int j = 0; j < SS; j++) acc = fmaf(pl[j], opb[(long)j * H + n], acc);
    w.Wbuf[(long)g * H + n] = acc;
  }
}

__global__ __launch_bounds__(NT) void assemble_k(IN in, WS w) {
  long idx = (long)blockIdx.x * NT + threadIdx.x;
  if (idx >= (long)GG * H2) return;
  long g = idx / H2;
  int k = (int)(idx - g * H2);
  int s = (int)(g & 127);
  float t;
  if (k < H) t = (s == 0) ? in.attn_h[k] : w.AO[g * H + k];
  else t = w.dialogue[g * H + (k - H)];
  w.out_spop[idx] = w.h_buf[idx] + t;
}

// ================= host =================

extern "C" void kernel_launch(void* const* d_in, const int* in_sizes, int n_in,
                              void* d_out, int out_size, void* d_ws, size_t ws_size,
                              hipStream_t stream) {
  IN in;
  in.chat_ids = (const int*)d_in[0];
  in.speaker_info = (const int*)d_in[1];
  in.inputs = (const int*)d_in[4];
  in.emb = (const float*)d_in[5];
  in.d_wih = (const float*)d_in[6];  in.d_whh = (const float*)d_in[7];
  in.d_bih = (const float*)d_in[8];  in.d_bhh = (const float*)d_in[9];
  in.g_wih = (const float*)d_in[10]; in.g_whh = (const float*)d_in[11];
  in.g_bih = (const float*)d_in[12]; in.g_bhh = (const float*)d_in[13];
  in.s_wih = (const float*)d_in[14]; in.s_whh = (const float*)d_in[15];
  in.s_bih = (const float*)d_in[16]; in.s_bhh = (const float*)d_in[17];
  in.wq = (const float*)d_in[18];  in.bq = (const float*)d_in[19];
  in.wk = (const float*)d_in[20];  in.bk = (const float*)d_in[21];
  in.wv = (const float*)d_in[22];  in.bv = (const float*)d_in[23];
  in.h0 = (const float*)d_in[24];  in.d_h0 = (const float*)d_in[25];
  in.attn_h = (const float*)d_in[26];

  char* base = (char*)d_ws;
  size_t off = 0;
  auto A = [&](size_t bytes) -> void* {
    size_t r = (off + 255) & ~(size_t)255;
    off = r + bytes;
    return (void*)(base + r);
  };
  WS w;
  w.flags1 = (int*)A(NWG * 16 * 4);
  w.Mqk = (float*)A((size_t)H * H * 4);
  w.Gsum = (float*)A((size_t)H3 * H * 4);
  w.cu = (float*)A(H * 4);
  w.vkq = (float*)A(H * 4);
  w.cb = (float*)A(4);
  w.cvs = (float*)A(H6 * 4);
  w.ch0s = (float*)A(H6 * 4);
  w.cvg = (float*)A(H3 * 4);
  w.chg0 = (float*)A(H3 * 4);
  w.ghs0 = (float*)A(H6 * 4);
  w.Ms = (float*)A((size_t)H6 * H * 4);
  w.Mg = (float*)A((size_t)H3 * H * 4);
  {
    void* r1 = A((size_t)GG * H6 * 4);  // max(gi_d [GG*H3], GIS [GG*H6])
    w.gi_d = (float*)r1;
    w.GIS = (float*)r1;
  }
  w.gi_bf = (uint32*)A((size_t)GG * H3 * 2);
  w.U_bf = (uint32*)A((size_t)GG * H * 2);
  w.dialogue = (float*)A((size_t)GG * H * 4);
  w.U = (float*)A((size_t)GG * H * 4);
  w.cvec = (float*)A(GG * 4);
  w.GIG = (float*)A((size_t)GG * H3 * 4);
  w.gh_dbuf = (float*)A((size_t)2 * BB * H3 * 4);
  w.sp_global = (float*)A((size_t)BB * H2 * 4);
  w.op_buf = (float*)A((size_t)SS * H * 4);
  w.op_tag = (u64*)A((size_t)H * 8);
  w.h_tag = (u64*)A((size_t)H2 * 8);
  w.sc_tag = (u64*)A((size_t)2 * SS * 8);
  w.probs_buf = (float*)A((size_t)GG * SS * 4);
  w.h_buf = (float*)A((size_t)GG * H2 * 4);
  w.Wbuf = (float*)A((size_t)GG * H * 4);
  w.AO = (float*)A((size_t)GG * H * 4);
  w.out_op = (float*)d_out;
  w.out_spop = (float*)d_out + (size_t)GG * H;

  (void)hipFuncSetAttribute((const void*)coop_main, hipFuncAttributeMaxDynamicSharedMemorySize, DYN_LDS);

  (void)hipMemsetAsync(w.flags1, 0, NWG * 16 * 4, stream);
  (void)hipMemsetAsync(w.op_tag, 0, (size_t)H * 8, stream);
  (void)hipMemsetAsync(w.h_tag, 0, (size_t)H2 * 8, stream);
  (void)hipMemsetAsync(w.sc_tag, 0, (size_t)2 * SS * 8, stream);

  const long NG = (long)H3 * H;
  prep1_k<<<(int)((NG + 2 * H + 1 + NT - 1) / NT), NT, 0, stream>>>(in, w);
  prep2_k<<<(H6 + H3 + H6 + 3) / 4, NT, 0, stream>>>(in, w);

  // Mqk = wq^T @ wk
  gemm_k<<<dim3(H / 64, H / 64), NT, 0, stream>>>(in.wq, 1, H, in.wk, H, w.Mqk, H, H, H);
  // Ms = s_wihA @ wv ; Mg = g_wihA @ wv
  mgemm_k<<<dim3(H / 128, H6 / 128), NT, 0, stream>>>(in.s_wih, H2, nullptr, in.wv, H, 0, nullptr, w.Ms, H, H);
  mgemm_k<<<dim3(H / 128, H3 / 128), NT, 0, stream>>>(in.g_wih, H3, nullptr, in.wv, H, 0, nullptr, w.Mg, H, H);
  // gi_d = emb[inputs] @ d_wih^T + d_bih, then pack to bf16x2
  mgemm_k<<<dim3(H3 / 128, GG / 128), NT, 0, stream>>>(in.emb, H, in.inputs, in.d_wih, H, 1, in.d_bih, w.gi_d, H3, H);
  pack_k<<<(int)(((long)GG * H3 / 2 + NT - 1) / NT), NT, 0, stream>>>(w.gi_d, w.gi_bf, (long)GG * H3 / 2);
  coop_rnnD<<<NWG, NTM, 0, stream>>>(in, w);

  // U = dialogue @ Mqk ; GIS = dialogue @ s_wihB^T + s_bih ; GIG = dialogue @ Gsum^T + g_bih
  mgemm_k<<<dim3(H / 128, GG / 128), NT, 0, stream>>>(w.dialogue, H, nullptr, w.Mqk, H, 0, nullptr, w.U, H, H);
  mgemm_k<<<dim3(H6 / 128, GG / 128), NT, 0, stream>>>(w.dialogue, H, nullptr, in.s_wih + H, H2, 1, in.s_bih, w.GIS, H6, H);
  mgemm_k<<<dim3(H3 / 128, GG / 128), NT, 0, stream>>>(w.dialogue, H, nullptr, w.Gsum, H, 1, in.g_bih, w.GIG, H3, H);
  fixup_u_k<<<(GG * H + NT - 1) / NT, NT, 0, stream>>>(w);
  pack_k<<<(int)(((long)GG * H / 2 + NT - 1) / NT), NT, 0, stream>>>(w.U, w.U_bf, (long)GG * H / 2);
  cvec_k<<<GG / 4, NT, 0, stream>>>(w);

  coop_main<<<NWG, NTM, DYN_LDS, stream>>>(in, w);

  epi_W_k<<<GG, NT, 0, stream>>>(w);
  // AO = Wbuf @ wv^T + bv
  mgemm_k<<<dim3(H / 128, GG / 128), NT, 0, stream>>>(w.Wbuf, H, nullptr, in.wv, H, 1, in.bv, w.AO, H, H);
  assemble_k<<<(int)(((long)GG * H2 + NT - 1) / NT), NT, 0, stream>>>(in, w);
}